// Round 10
// baseline (5082.498 us; speedup 1.0000x reference)
//
#include <hip/hip_runtime.h>
#include <cstdint>
#include <cstddef>

#define B_MOL 512
#define A_PER 64
#define ED_PER 256
#define N_ATOMS (B_MOL * A_PER)   // 32768
#define N_DIR (B_MOL * ED_PER)    // 131072
#define N_UND (B_MOL * 128)       // 65536
#define HID 256
#define OUT_STRIDE 12289
#define AP 40   // LDS pitch (shorts) for a 32-wide k row (mgemm)
#define CP 72   // combined-plane LDS pitch (shorts): 32 hi | 32 lo | 8 pad

typedef __attribute__((ext_vector_type(8))) short bf16x8;
typedef __attribute__((ext_vector_type(8))) unsigned short u16x8;
typedef __attribute__((ext_vector_type(4))) float f32x4;

#define MFMA(a, b, c) __builtin_amdgcn_mfma_f32_16x16x32_bf16(a, b, c, 0, 0, 0)

__device__ __forceinline__ float b2f(unsigned short s) {
  return __builtin_bit_cast(float, (unsigned)s << 16);
}
// split fp32 -> (hi, lo) bf16 planes: x ~= hi + lo, |err| <~ 2^-16 |x|
__device__ __forceinline__ void split2(float v, unsigned short& h, unsigned short& l) {
  unsigned ub = __builtin_bit_cast(unsigned, v);
  h = (unsigned short)(ub >> 16);
  float fh = __builtin_bit_cast(float, ub & 0xffff0000u);
  float r = v - fh;
  l = (unsigned short)(__builtin_bit_cast(unsigned, r) >> 16);
}
// fp32 -> bf16 round-to-nearest-even (for the fb single plane)
__device__ __forceinline__ unsigned short f2bf_rne(float v) {
  unsigned u = __builtin_bit_cast(unsigned, v);
  u += 0x7FFFu + ((u >> 16) & 1u);
  return (unsigned short)(u >> 16);
}
__device__ __forceinline__ int e_src(int e) {
  return (e < 64) ? e : (e < 128) ? (e - 64)
       : (e < 192) ? ((e - 127) & 63) : ((e - 190) & 63);
}

// ---------------------------------------------------------------------------
// convAll: ALL weight pre-converts in one launch. dst[n][k] split planes.
// Blocks [3232, 7328): f_bonds -> single bf16 (RNE) plane [131072][128].
// ---------------------------------------------------------------------------
__global__ __launch_bounds__(256) void convAll(
    const float* Wi, const float* Wh, const float* Wo,
    const float* Wq, const float* Wk, const float* Wv,
    const float* Wattn, const float* Wvc, const float* Wvv,
    const float* A1, const float* A2, const float* B1, const float* B2,
    const float* fbF, unsigned short* fbT,
    unsigned short* WiTh, unsigned short* WiTl,
    unsigned short* WhTh, unsigned short* WhTl,
    unsigned short* WoTh, unsigned short* WoTl,
    unsigned short* WqkvTh, unsigned short* WqkvTl,
    unsigned short* WaTh, unsigned short* WaTl,
    unsigned short* WcvTh, unsigned short* WcvTl,
    unsigned short* A1Th, unsigned short* A1Tl,
    unsigned short* A2Th, unsigned short* A2Tl,
    unsigned short* B1Th, unsigned short* B1Tl,
    unsigned short* B2Th, unsigned short* B2Tl) {
  int b = blockIdx.x;
  if (b >= 3232) {  // f_bonds convert: 32 edges per block, 8 thr/edge
    int e = (b - 3232) * 32 + (threadIdx.x >> 3);
    int ks = (threadIdx.x & 7) * 16;
    const float* s = fbF + (size_t)e * 111;
    u16x8 o0 = {0,0,0,0,0,0,0,0}, o1 = {0,0,0,0,0,0,0,0};
#pragma unroll
    for (int z = 0; z < 8; ++z) {
      int k = ks + z;
      if (k < 111) o0[z] = f2bf_rne(s[k]);
    }
#pragma unroll
    for (int z = 0; z < 8; ++z) {
      int k = ks + 8 + z;
      if (k < 111) o1[z] = f2bf_rne(s[k]);
    }
    *(u16x8*)&fbT[(size_t)e * 128 + ks] = o0;
    *(u16x8*)&fbT[(size_t)e * 128 + ks + 8] = o1;
    return;
  }
  const float *src = nullptr, *src2 = nullptr;
  unsigned short *dh = nullptr, *dl = nullptr;
  int K = 256, N = 256, Kp = 256, mode = 0, n = 0;
  if (b < 2048) {
    int seg = b >> 8; n = b & 255;
    switch (seg) {
      case 0: src = Wi; dh = WiTh; dl = WiTl; K = 111; Kp = 128; break;
      case 1: src = Wh; dh = WhTh; dl = WhTl; break;
      case 2: src = Wo; dh = WoTh; dl = WoTl; K = 354; Kp = 384; mode = 1; break;
      case 3: src = Wq; dh = WqkvTh; dl = WqkvTl; break;
      case 4: src = Wk; dh = WqkvTh + 65536; dl = WqkvTl + 65536; break;
      case 5: src = Wv; dh = WqkvTh + 131072; dl = WqkvTl + 131072; break;
      case 6: src = Wattn; dh = WaTh; dl = WaTl; break;
      default: src = Wvc; src2 = Wvv; dh = WcvTh; dl = WcvTl; K = 512; Kp = 512; mode = 2; break;
    }
  } else if (b < 2560) { n = b - 2048; src = A1; dh = A1Th; dl = A1Tl; K = 256; N = 512; Kp = 256; }
  else if (b < 2688)   { n = b - 2560; src = A2; dh = A2Th; dl = A2Tl; K = 512; N = 128; Kp = 512; }
  else if (b < 3200)   { n = b - 2688; src = B1; dh = B1Th; dl = B1Tl; K = 512; N = 512; Kp = 512; }
  else                 { n = b - 3200; src = B2; dh = B2Th; dl = B2Tl; K = 512; N = 32;  Kp = 512; }
  for (int k = threadIdx.x; k < Kp; k += 256) {
    float v = 0.f;
    if (mode == 0) { if (k < K) v = src[(size_t)k * N + n]; }
    else if (mode == 1) {
      if (k < 256) v = src[(size_t)(98 + k) * 256 + n];
      else if (k < 354) v = src[(size_t)(k - 256) * 256 + n];
    } else {
      v = (k < 256) ? src[(size_t)n * 256 + k] : src2[(size_t)n * 256 + (k - 256)];
    }
    unsigned short h_, l_;
    split2(v, h_, l_);
    dh[(size_t)n * Kp + k] = h_;
    dl[(size_t)n * Kp + k] = l_;
  }
}

// ---------------------------------------------------------------------------
// mgemm: split-bf16 MFMA GEMM. 128x128 tile, BK=32, 256 thr (4 waves, 2x2),
// 64x64/wave, 3 MFMA per frag-pair (2 for AMODE 6: single-plane A).
// B pre-split/pre-transposed global [N][Kp] planes (BTh/BTl, ldb=Kp).
// AMODE 0: fp32 A [M][lda]; 1: split A planes; 2: concat fp32 asumF|f_atoms;
//       3: split afat | fp32 prev_hid; 5: bond combine relu(P1[a0]+P2[a1]+b);
//       6: SINGLE bf16 plane A [M][lda] (fb), 2 MFMA/frag.
// outmode 0: split planes; 1: fp32 (+outcol); 2: atom-head; 3: bond-head.
// ---------------------------------------------------------------------------
template <int AMODE>
__launch_bounds__(256, 3)
__global__ void mgemm(const void* Aa_, const void* Ab_, const void* Ac_, const void* Ad_,
                      const unsigned short* __restrict__ BTh,
                      const unsigned short* __restrict__ BTl, int ldb,
                      const unsigned short* addH, const unsigned short* addL,
                      const float* __restrict__ bias,
                      const float* __restrict__ abias,
                      void* outA, void* outB,
                      int M, int N, int K, int lda, int ldco, int outcol,
                      int relu, int outmode) {
  __shared__ unsigned short AsH[128 * AP], AsL[128 * AP];
  __shared__ unsigned short BsH[128 * AP], BsL[128 * AP];
  const int tid = threadIdx.x;
  const int lane = tid & 63;
  const int l15 = lane & 15, l4 = lane >> 4;
  const int w = tid >> 6;
  const int wr = (w >> 1) * 64, wc = (w & 1) * 64;
  const int tileM = blockIdx.x * 128, tileN = blockIdx.y * 128;
  const int srow = tid >> 1;           // staging row 0..127
  const int sks = (tid & 1) * 16;      // staging k-seg {0,16}

  int rem = N - tileN - wc;
  int bnMax = rem >= 64 ? 4 : (rem > 0 ? (rem >> 4) : 0);

  f32x4 zf = {0.f, 0.f, 0.f, 0.f};
  f32x4 acc[4][4];
#pragma unroll
  for (int i = 0; i < 4; ++i)
#pragma unroll
    for (int j = 0; j < 4; ++j) acc[i][j] = zf;

  const int nkb = (K + 31) >> 5;
  for (int kb = 0; kb < nkb; ++kb) {
    __syncthreads();
    const int k0 = kb * 32 + sks;
    // ---- stage A ----
    {
      const int row = tileM + srow;
      if (AMODE == 6) {
        const unsigned short* Ah = (const unsigned short*)Aa_;
        size_t bse = (size_t)row * lda + k0;
        *(u16x8*)&AsH[srow * AP + sks]     = *(const u16x8*)&Ah[bse];
        *(u16x8*)&AsH[srow * AP + sks + 8] = *(const u16x8*)&Ah[bse + 8];
      } else if (AMODE == 1 || (AMODE == 3 && k0 < 256)) {
        const unsigned short* Ah = (const unsigned short*)Aa_;
        const unsigned short* Al = (const unsigned short*)Ab_;
        size_t bse = (AMODE == 3) ? ((size_t)row * 256 + k0)
                                  : ((size_t)row * lda + k0);
        *(u16x8*)&AsH[srow * AP + sks]     = *(const u16x8*)&Ah[bse];
        *(u16x8*)&AsH[srow * AP + sks + 8] = *(const u16x8*)&Ah[bse + 8];
        *(u16x8*)&AsL[srow * AP + sks]     = *(const u16x8*)&Al[bse];
        *(u16x8*)&AsL[srow * AP + sks + 8] = *(const u16x8*)&Al[bse + 8];
      } else if (AMODE == 5) {
        int mol = row >> 7, u = row & 127;
        int a0 = (u < 64) ? u : (u - 64);
        int a1v = (u < 64) ? ((u + 1) & 63) : ((u - 62) & 63);
        size_t p1 = (size_t)(mol * 64 + a0) * 512 + k0;
        size_t p2 = (size_t)(mol * 64 + a1v) * 512 + k0;
        const unsigned short* P1h = (const unsigned short*)Aa_;
        const unsigned short* P1l = (const unsigned short*)Ab_;
        const unsigned short* P2h = (const unsigned short*)Ac_;
        const unsigned short* P2l = (const unsigned short*)Ad_;
        u16x8 x1h[2] = {*(const u16x8*)&P1h[p1], *(const u16x8*)&P1h[p1 + 8]};
        u16x8 x1l[2] = {*(const u16x8*)&P1l[p1], *(const u16x8*)&P1l[p1 + 8]};
        u16x8 x2h[2] = {*(const u16x8*)&P2h[p2], *(const u16x8*)&P2h[p2 + 8]};
        u16x8 x2l[2] = {*(const u16x8*)&P2l[p2], *(const u16x8*)&P2l[p2 + 8]};
#pragma unroll
        for (int c = 0; c < 2; ++c) {
          u16x8 hv, lv;
#pragma unroll
          for (int z = 0; z < 8; ++z) {
            float v = b2f(x1h[c][z]) + b2f(x1l[c][z])
                    + b2f(x2h[c][z]) + b2f(x2l[c][z]) + abias[k0 + c * 8 + z];
            v = fmaxf(v, 0.f);
            unsigned short h_, l_;
            split2(v, h_, l_);
            hv[z] = h_; lv[z] = l_;
          }
          *(u16x8*)&AsH[srow * AP + sks + c * 8] = hv;
          *(u16x8*)&AsL[srow * AP + sks + c * 8] = lv;
        }
      } else {
        u16x8 hv0 = {0,0,0,0,0,0,0,0}, lv0 = {0,0,0,0,0,0,0,0};
        u16x8 hv1 = {0,0,0,0,0,0,0,0}, lv1 = {0,0,0,0,0,0,0,0};
#pragma unroll
        for (int z = 0; z < 16; ++z) {
          int k = k0 + z;
          float v = 0.f;
          if (AMODE == 0) {
            if (k < K) v = ((const float*)Aa_)[(size_t)row * lda + k];
          } else if (AMODE == 2) {
            if (k < 256) v = ((const float*)Aa_)[(size_t)row * 256 + k];
            else if (k < 354) v = ((const float*)Ab_)[(size_t)row * 98 + (k - 256)];
          } else {  // AMODE 3, k0 >= 256
            v = ((const float*)Ac_)[(size_t)row * 256 + (k - 256)];
          }
          unsigned short h_, l_;
          split2(v, h_, l_);
          if (z < 8) { hv0[z] = h_; lv0[z] = l_; }
          else       { hv1[z - 8] = h_; lv1[z - 8] = l_; }
        }
        *(u16x8*)&AsH[srow * AP + sks]     = hv0;
        *(u16x8*)&AsH[srow * AP + sks + 8] = hv1;
        *(u16x8*)&AsL[srow * AP + sks]     = lv0;
        *(u16x8*)&AsL[srow * AP + sks + 8] = lv1;
      }
    }
    // ---- stage B ----
    {
      const int n = tileN + srow;
      if (n < N) {
        size_t bb = (size_t)n * ldb + k0;
        *(u16x8*)&BsH[srow * AP + sks]     = *(const u16x8*)&BTh[bb];
        *(u16x8*)&BsH[srow * AP + sks + 8] = *(const u16x8*)&BTh[bb + 8];
        *(u16x8*)&BsL[srow * AP + sks]     = *(const u16x8*)&BTl[bb];
        *(u16x8*)&BsL[srow * AP + sks + 8] = *(const u16x8*)&BTl[bb + 8];
      } else {
        u16x8 z8 = {0,0,0,0,0,0,0,0};
        *(u16x8*)&BsH[srow * AP + sks]     = z8;
        *(u16x8*)&BsH[srow * AP + sks + 8] = z8;
        *(u16x8*)&BsL[srow * AP + sks]     = z8;
        *(u16x8*)&BsL[srow * AP + sks + 8] = z8;
      }
    }
    __syncthreads();
    // ---- compute ----
    bf16x8 ah[4], al[4];
#pragma unroll
    for (int am = 0; am < 4; ++am) {
      int ar = wr + am * 16 + l15;
      ah[am] = *(const bf16x8*)&AsH[ar * AP + l4 * 8];
      if (AMODE != 6) al[am] = *(const bf16x8*)&AsL[ar * AP + l4 * 8];
    }
#pragma unroll
    for (int bn = 0; bn < 4; ++bn) {
      if (bn < bnMax) {
        int br = wc + bn * 16 + l15;
        bf16x8 bh = *(const bf16x8*)&BsH[br * AP + l4 * 8];
        bf16x8 bl = *(const bf16x8*)&BsL[br * AP + l4 * 8];
#pragma unroll
        for (int am = 0; am < 4; ++am) {
          acc[am][bn] = MFMA(ah[am], bh, acc[am][bn]);
          acc[am][bn] = MFMA(ah[am], bl, acc[am][bn]);
          if (AMODE != 6) acc[am][bn] = MFMA(al[am], bh, acc[am][bn]);
        }
      }
    }
  }

  // ---- epilogue ----
#pragma unroll
  for (int am = 0; am < 4; ++am) {
#pragma unroll
    for (int bn = 0; bn < 4; ++bn) {
      if (bn >= bnMax) continue;
      int col = tileN + wc + bn * 16 + l15;
      float bs = bias ? bias[col] : 0.f;
#pragma unroll
      for (int r = 0; r < 4; ++r) {
        size_t row = (size_t)tileM + wr + am * 16 + l4 * 4 + r;
        float v = acc[am][bn][r] + bs;
        if (addH) v += b2f(addH[row * 256 + col]) + b2f(addL[row * 256 + col]);
        if (relu) v = fmaxf(v, 0.f);
        if (outmode == 0) {
          unsigned short h_, l_;
          split2(v, h_, l_);
          ((unsigned short*)outA)[row * (size_t)ldco + col] = h_;
          ((unsigned short*)outB)[row * (size_t)ldco + col] = l_;
        } else if (outmode == 1) {
          ((float*)outA)[row * (size_t)ldco + outcol + col] = v;
        } else if (outmode == 2) {
          int mol = (int)(row >> 6), t = (int)(row & 63);
          ((float*)outA)[(size_t)mol * OUT_STRIDE + 4096 + t * 128 + col] = v;
        } else {
          int mol = (int)(row >> 7), u = (int)(row & 127);
          ((float*)outA)[(size_t)mol * OUT_STRIDE + u * 32 + col] = v;
        }
      }
    }
  }
}

// ---------------------------------------------------------------------------
// msg_f5: PERSISTENT fused DMPNN — all 9 iterations inside one kernel.
// One block per molecule (owns all 256 edges across ALL iterations -> only
// block-local sync needed; zero cross-block data flow). 1024 thr = 16 waves
// (4M x 4N), wave tile 64x64, acc[4][4], BK=32, combined-plane LDS 73,728 B
// (2 blocks/CU). Per iteration: phase 1 acc = fbT@Wi (2 MFMA/frag),
// mid-relu; phase 2 acc += m@Wh with fused a_sum staging (3 MFMA/frag);
// epilogue h = relu(acc) in-place; __threadfence() (agent fence, L1 inv)
// + barrier before next iteration's reads of h.
// ---------------------------------------------------------------------------
__launch_bounds__(1024)
__global__ void msg_f5(float* h,
                       const unsigned short* __restrict__ WhTh,
                       const unsigned short* __restrict__ WhTl,
                       const unsigned short* __restrict__ WiTh,
                       const unsigned short* __restrict__ WiTl,
                       const unsigned short* __restrict__ fbT,
                       int iters) {
  extern __shared__ char smem_[];
  unsigned short* AsC = (unsigned short*)smem_;              // 256*72*2 = 36864 B
  unsigned short* BsC = (unsigned short*)(smem_ + 36864);    // 36864 B
  const int tid = threadIdx.x;
  const int lane = tid & 63, l15 = lane & 15, l4 = lane >> 4;
  const int w = tid >> 6;          // 0..15
  const int wm = (w >> 2) * 64;    // row base: 0,64,128,192
  const int wn = (w & 3) * 64;     // col base: 0,64,128,192
  const int mol = blockIdx.x;
  const int arow = tid >> 2;       // staging row 0..255 (edge id, identity)
  const int aks = (tid & 3) * 8;   // staging k sub-seg {0,8,16,24}

  // per-staged-edge graph indices (block owns whole molecule; edge = arow)
  const int sA = e_src(arow);
  const int rvA = (arow < 128) ? (arow + 128) : (arow - 128);
  const int i0 = (sA + 63) & 63;
  const int i1 = 64 + ((sA + 62) & 63);
  const int i2 = 128 + sA;
  const int i3 = 192 + sA;
  const size_t hbase = (size_t)mol * 256 * 256;
  const size_t fbb = (size_t)(mol * 256 + arow) * 128;

  for (int d = 0; d < iters; ++d) {
    f32x4 acc[4][4];
#pragma unroll
    for (int i = 0; i < 4; ++i)
#pragma unroll
      for (int j = 0; j < 4; ++j) acc[i][j] = (f32x4){0.f, 0.f, 0.f, 0.f};

    // ---- phase 1: acc = fbT @ Wi (K=128 padded -> 4 chunks of 32) ----
    for (int kb = 0; kb < 4; ++kb) {
      __syncthreads();
      {
        *(u16x8*)&AsC[arow * CP + aks] = *(const u16x8*)&fbT[fbb + kb * 32 + aks];
      }
      {
        size_t bb = (size_t)arow * 128 + kb * 32 + aks;  // Wi pitch 128
        *(u16x8*)&BsC[arow * CP + aks]      = *(const u16x8*)&WiTh[bb];
        *(u16x8*)&BsC[arow * CP + 32 + aks] = *(const u16x8*)&WiTl[bb];
      }
      __syncthreads();
      bf16x8 ah[4];
#pragma unroll
      for (int am = 0; am < 4; ++am) {
        int ar = wm + am * 16 + l15;
        ah[am] = *(const bf16x8*)&AsC[ar * CP + l4 * 8];
      }
#pragma unroll
      for (int bn = 0; bn < 4; ++bn) {
        int br = wn + bn * 16 + l15;
        bf16x8 bh = *(const bf16x8*)&BsC[br * CP + l4 * 8];
        bf16x8 bl = *(const bf16x8*)&BsC[br * CP + 32 + l4 * 8];
#pragma unroll
        for (int am = 0; am < 4; ++am) {
          acc[am][bn] = MFMA(ah[am], bh, acc[am][bn]);
          acc[am][bn] = MFMA(ah[am], bl, acc[am][bn]);
        }
      }
    }
    // mid-relu -> acc holds h0
#pragma unroll
    for (int i = 0; i < 4; ++i)
#pragma unroll
      for (int j = 0; j < 4; ++j)
#pragma unroll
        for (int r = 0; r < 4; ++r) acc[i][j][r] = fmaxf(acc[i][j][r], 0.f);

    // ---- phase 2: acc += m @ Wh, K=256 (8 chunks); fused a_sum staging ----
    for (int kb = 0; kb < 8; ++kb) {
      __syncthreads();
      {
        const int c0 = kb * 32 + aks;
        f32x4 m0, m1;
        {
          const float* p = &h[hbase + (size_t)i0 * 256 + c0];
          m0 = *(const f32x4*)p;
          m1 = *(const f32x4*)(p + 4);
        }
        {
          const float* p = &h[hbase + (size_t)i1 * 256 + c0];
          m0 += *(const f32x4*)p;
          m1 += *(const f32x4*)(p + 4);
        }
        {
          const float* p = &h[hbase + (size_t)i2 * 256 + c0];
          m0 += *(const f32x4*)p;
          m1 += *(const f32x4*)(p + 4);
        }
        {
          const float* p = &h[hbase + (size_t)i3 * 256 + c0];
          m0 += *(const f32x4*)p;
          m1 += *(const f32x4*)(p + 4);
        }
        {
          const float* p = &h[hbase + (size_t)rvA * 256 + c0];
          m0 -= *(const f32x4*)p;
          m1 -= *(const f32x4*)(p + 4);
        }
        u16x8 hv, lv;
#pragma unroll
        for (int z = 0; z < 4; ++z) {
          unsigned short h_, l_;
          split2(m0[z], h_, l_); hv[z] = h_; lv[z] = l_;
          split2(m1[z], h_, l_); hv[4 + z] = h_; lv[4 + z] = l_;
        }
        *(u16x8*)&AsC[arow * CP + aks]      = hv;
        *(u16x8*)&AsC[arow * CP + 32 + aks] = lv;
      }
      {
        size_t bb = (size_t)arow * 256 + kb * 32 + aks;  // Wh pitch 256
        *(u16x8*)&BsC[arow * CP + aks]      = *(const u16x8*)&WhTh[bb];
        *(u16x8*)&BsC[arow * CP + 32 + aks] = *(const u16x8*)&WhTl[bb];
      }
      __syncthreads();
      bf16x8 ah[4], al[4];
#pragma unroll
      for (int am = 0; am < 4; ++am) {
        int ar = wm + am * 16 + l15;
        ah[am] = *(const bf16x8*)&AsC[ar * CP + l4 * 8];
        al[am] = *(const bf16x8*)&AsC[ar * CP + 32 + l4 * 8];
      }
#pragma unroll
      for (int bn = 0; bn < 4; ++bn) {
        int br = wn + bn * 16 + l15;
        bf16x8 bh = *(const bf16x8*)&BsC[br * CP + l4 * 8];
        bf16x8 bl = *(const bf16x8*)&BsC[br * CP + 32 + l4 * 8];
#pragma unroll
        for (int am = 0; am < 4; ++am) {
          acc[am][bn] = MFMA(ah[am], bh, acc[am][bn]);
          acc[am][bn] = MFMA(ah[am], bl, acc[am][bn]);
          acc[am][bn] = MFMA(al[am], bh, acc[am][bn]);
        }
      }
    }

    // ---- epilogue: h = relu(acc) fp32, in-place (block owns its rows) ----
#pragma unroll
    for (int am = 0; am < 4; ++am) {
#pragma unroll
      for (int r = 0; r < 4; ++r) {
        int row = wm + am * 16 + l4 * 4 + r;
        size_t rowb = hbase + (size_t)row * 256;
#pragma unroll
        for (int bn = 0; bn < 4; ++bn) {
          int col = wn + bn * 16 + l15;
          h[rowb + col] = fmaxf(acc[am][bn][r], 0.f);
        }
      }
    }
    // make h writes visible to all waves of this block (agent fence drains
    // vmcnt + invalidates L1); next iteration's first chunk barrier then
    // guarantees every wave's epilogue completed before any h read.
    __threadfence();
  }
}

// a_sum over the 4 incoming directed edges of each atom (fp32 h -> fp32 out)
__global__ __launch_bounds__(256) void asum_f(const float* __restrict__ h,
                                              float* __restrict__ out) {
  int g = blockIdx.x * 256 + threadIdx.x;  // 32768 atoms x 32 chunks of 8
  int atom = g >> 5, cc = (g & 31) << 3;
  int mol = atom >> 6, t = atom & 63;
  const float* hb = h + (size_t)mol * ED_PER * HID;
  int e0 = (t + 63) & 63;
  int e1 = 64 + ((t + 62) & 63);
  int e2 = 128 + t;
  int e3 = 192 + t;
  f32x4 s0 = {0.f, 0.f, 0.f, 0.f}, s1 = {0.f, 0.f, 0.f, 0.f};
#define ACC_E(ee) { \
    const float* p = hb + (size_t)(ee) * HID + cc; \
    s0 += *(const f32x4*)p; \
    s1 += *(const f32x4*)(p + 4); }
  ACC_E(e0); ACC_E(e1); ACC_E(e2); ACC_E(e3);
#undef ACC_E
  *(f32x4*)&out[(size_t)atom * HID + cc] = s0;
  *(f32x4*)&out[(size_t)atom * HID + cc + 4] = s1;
}

// flash attention, fp32 qkv in, split ctx out: one wave per (mol, head)
__global__ __launch_bounds__(64) void attn_k(const float* __restrict__ qkv,
                                             unsigned short* __restrict__ ctxH,
                                             unsigned short* __restrict__ ctxL) {
  __shared__ float kls[64 * 32];
  __shared__ float vls[64 * 32];
  int mol = blockIdx.x >> 3, head = blockIdx.x & 7;
  int lane = threadIdx.x;
  size_t rb = ((size_t)(mol * 64 + lane)) * 768 + head * 32;
#pragma unroll
  for (int c = 0; c < 8; ++c) {
    *(float4*)(kls + lane * 32 + c * 4) = *(const float4*)(qkv + rb + 256 + c * 4);
    *(float4*)(vls + lane * 32 + c * 4) = *(const float4*)(qkv + rb + 512 + c * 4);
  }
  float q[32];
#pragma unroll
  for (int d = 0; d < 32; ++d) q[d] = qkv[rb + d];
  __syncthreads();
  float mx = -1e30f, l = 0.f;
  float acc[32];
#pragma unroll
  for (int d = 0; d < 32; ++d) acc[d] = 0.f;
  for (int j = 0; j < 64; ++j) {
    float s = 0.f;
#pragma unroll
    for (int d = 0; d < 32; ++d) s += q[d] * kls[j * 32 + d];
    s *= 0.17677669529663687f;  // 1/sqrt(32)
    float nm = fmaxf(mx, s);
    float co = __expf(mx - nm);
    float p = __expf(s - nm);
    l = l * co + p;
#pragma unroll
    for (int d = 0; d < 32; ++d) acc[d] = acc[d] * co + p * vls[j * 32 + d];
    mx = nm;
  }
  float inv = 1.f / l;
  size_t ob = ((size_t)(mol * 64 + lane)) * 256 + head * 32;
#pragma unroll
  for (int d = 0; d < 32; ++d) {
    unsigned short h_, l_;
    split2(acc[d] * inv, h_, l_);
    ctxH[ob + d] = h_;
    ctxL[ob + d] = l_;
  }
}

// graph_vecs[mol][c] = sum over 64 atoms (split atomf planes)
__global__ __launch_bounds__(256) void gv_k(const unsigned short* __restrict__ afH,
                                            const unsigned short* __restrict__ afL,
                                            float* __restrict__ gv) {
  int mol = blockIdx.x, c = threadIdx.x;
  float s = 0.f;
  for (int a = 0; a < 64; ++a) {
    size_t i = ((size_t)mol * 64 + a) * 256 + c;
    s += b2f(afH[i]) + b2f(afL[i]);
  }
  gv[mol * 256 + c] = s;
}

// graph head: relu(gv@G1+g1)@G2+g2 -> out[mol*12289+12288]
__global__ __launch_bounds__(512) void gh_k(const float* __restrict__ gv, const float* __restrict__ G1,
                                            const float* __restrict__ g1, const float* __restrict__ G2,
                                            const float* __restrict__ g2, float* __restrict__ out) {
  __shared__ float xs[256];
  __shared__ float red[512];
  int mol = blockIdx.x, j = threadIdx.x;
  if (j < 256) xs[j] = gv[mol * 256 + j];
  __syncthreads();
  float s = 0.f;
  for (int k = 0; k < 256; ++k) s += xs[k] * G1[k * 512 + j];
  s = fmaxf(s + g1[j], 0.f);
  red[j] = s * G2[j];
  __syncthreads();
  for (int st = 256; st > 0; st >>= 1) {
    if (j < st) red[j] += red[j + st];
    __syncthreads();
  }
  if (j == 0) out[(size_t)mol * OUT_STRIDE + 12288] = red[0] + g2[0];
}

extern "C" void kernel_launch(void* const* d_in, const int* in_sizes, int n_in,
                              void* d_out, int out_size, void* d_ws, size_t ws_size,
                              hipStream_t stream) {
  (void)in_sizes; (void)n_in; (void)out_size; (void)ws_size;
  const float* f_atoms  = (const float*)d_in[0];
  const float* f_bonds  = (const float*)d_in[1];
  const float* prev_hid = (const float*)d_in[2];
  const float* W_i   = (const float*)d_in[7];
  const float* W_h   = (const float*)d_in[8];
  const float* W_o   = (const float*)d_in[9];
  const float* b_o   = (const float*)d_in[10];
  const float* Wq    = (const float*)d_in[11];
  const float* Wk    = (const float*)d_in[12];
  const float* Wv    = (const float*)d_in[13];
  const float* Wattn = (const float*)d_in[14];
  const float* W_vv  = (const float*)d_in[15];
  const float* W_vc  = (const float*)d_in[16];
  const float* A1    = (const float*)d_in[17];
  const float* a1    = (const float*)d_in[18];
  const float* A2    = (const float*)d_in[19];
  const float* a2    = (const float*)d_in[20];
  const float* B1    = (const float*)d_in[21];
  const float* b1    = (const float*)d_in[22];
  const float* B2    = (const float*)d_in[23];
  const float* b2b   = (const float*)d_in[24];
  const float* G1    = (const float*)d_in[25];
  const float* g1    = (const float*)d_in[26];
  const float* G2    = (const float*)d_in[27];
  const float* g2    = (const float*)d_in[28];
  float* out = (float*)d_out;

  // ---- workspace (~172.6 MB < known-good 187.3) ----
  char* base = (char*)d_ws;
  float* h = (float*)(base);                                   // 134.2 MB fp32
  // [134.2M, 167.8M): dual-purpose 32MB region —
  //   fbT (bf16 [131072][128]) during steps 0-2; asumF (fp32) from step 3 on.
  unsigned short* fbT = (unsigned short*)(base + 134217728);
  float* asumF = (float*)(base + 134217728);
  char* W0 = base + 167772160;                                 // weights ~4.8 MB
  unsigned short* WiTh   = (unsigned short*)(W0);
  unsigned short* WiTl   = (unsigned short*)(W0 + 65536);
  unsigned short* WhTh   = (unsigned short*)(W0 + 131072);
  unsigned short* WhTl   = (unsigned short*)(W0 + 262144);
  unsigned short* WoTh   = (unsigned short*)(W0 + 393216);
  unsigned short* WoTl   = (unsigned short*)(W0 + 589824);
  unsigned short* WqkvTh = (unsigned short*)(W0 + 786432);     // [768][256]
  unsigned short* WqkvTl = (unsigned short*)(W0 + 1179648);
  unsigned short* WaTh   = (unsigned short*)(W0 + 1572864);
  unsigned short* WaTl   = (unsigned short*)(W0 + 1703936);
  unsigned short* WcvTh  = (unsigned short*)(W0 + 1835008);
  unsigned short* WcvTl  = (unsigned short*)(W0 + 2097152);
  unsigned short* A1Th   = (unsigned short*)(W0 + 2359296);
  unsigned short* A1Tl   = (unsigned short*)(W0 + 2621440);
  unsigned short* A2Th   = (unsigned short*)(W0 + 2883584);
  unsigned short* A2Tl   = (unsigned short*)(W0 + 3014656);
  unsigned short* B1Th   = (unsigned short*)(W0 + 3145728);
  unsigned short* B1Tl   = (unsigned short*)(W0 + 3670016);
  unsigned short* B2Th   = (unsigned short*)(W0 + 4194304);
  unsigned short* B2Tl   = (unsigned short*)(W0 + 4227072);
  float* gvec            = (float*)(W0 + 4259840);
  // post-loop aliases (sequential-stream lifetimes audited):
  unsigned short* xAh  = (unsigned short*)(base);              // step 4-7
  unsigned short* xAl  = (unsigned short*)(base + 16777216);
  float* qkv           = (float*)(base + 33554432);            // step 5-6, 100.7 MB
  unsigned short* ctxh = (unsigned short*)(base + 134217728);  // step 6-7 (over asumF)
  unsigned short* ctxl = (unsigned short*)(base + 150994944);
  unsigned short* afh  = (unsigned short*)(base + 33554432);   // step 7-8 (over qkv)
  unsigned short* afl  = (unsigned short*)(base + 50331648);
  unsigned short* atfh = (unsigned short*)(base + 67108864);   // step 8-end
  unsigned short* atfl = (unsigned short*)(base + 83886080);
  unsigned short* t1h  = (unsigned short*)(base);              // step 9
  unsigned short* t1l  = (unsigned short*)(base + 33554432);
  unsigned short* P1h  = (unsigned short*)(base);              // step 10
  unsigned short* P1l  = (unsigned short*)(base + 33554432);
  unsigned short* P2h  = (unsigned short*)(base + 100663296);
  unsigned short* P2l  = (unsigned short*)(base + 134217728);

  // 0) all weight pre-converts + f_bonds bf16 plane in one launch
  convAll<<<7328, 256, 0, stream>>>(
      W_i, W_h, W_o, Wq, Wk, Wv, Wattn, W_vc, W_vv, A1, A2, B1, B2,
      f_bonds, fbT,
      WiTh, WiTl, WhTh, WhTl, WoTh, WoTl, WqkvTh, WqkvTl, WaTh, WaTl,
      WcvTh, WcvTl, A1Th, A1Tl, A2Th, A2Tl, B1Th, B1Tl, B2Th, B2Tl);

  // 1) h = h0 = relu(fbT @ W_i)  (single-plane A, fp32 out)
  mgemm<6><<<dim3(1024, 2), 256, 0, stream>>>(
      fbT, nullptr, nullptr, nullptr, WiTh, WiTl, 128,
      nullptr, nullptr, nullptr, nullptr,
      h, nullptr, N_DIR, 256, 128, 128, 256, 0, 1, 1);

  // 2) DMPNN loop: PERSISTENT — all 9 iterations in one launch, one block
  //    per molecule (block-local sync only; molecules independent)
  msg_f5<<<512, 1024, 73728, stream>>>(h, WhTh, WhTl, WiTh, WiTl, fbT, 9);

  // 3) a_in  (asumF overwrites fbT — fbT dead after the loop)
  asum_f<<<4096, 256, 0, stream>>>(h, asumF);
  // 4) a_feats = relu([asum | f_atoms] @ WoT + b_o)
  mgemm<2><<<dim3(256, 2), 256, 0, stream>>>(
      asumF, f_atoms, nullptr, nullptr, WoTh, WoTl, 384,
      nullptr, nullptr, b_o, nullptr,
      xAh, xAl, N_ATOMS, 256, 354, 0, 256, 0, 1, 0);
  // 5) qkv fused (N=768, fp32 out)
  mgemm<1><<<dim3(256, 6), 256, 0, stream>>>(
      xAh, xAl, nullptr, nullptr, WqkvTh, WqkvTl, 256,
      nullptr, nullptr, nullptr, nullptr,
      qkv, nullptr, N_ATOMS, 768, 256, 256, 768, 0, 0, 1);
  // 6) attention
  attn_k<<<4096, 64, 0, stream>>>(qkv, ctxh, ctxl);
  // 7) a_feats' = x + ctx @ Wattn   (addend = xA split)
  mgemm<1><<<dim3(256, 2), 256, 0, stream>>>(
      ctxh, ctxl, nullptr, nullptr, WaTh, WaTl, 256,
      xAh, xAl, nullptr, nullptr,
      afh, afl, N_ATOMS, 256, 256, 256, 256, 0, 0, 0);
  // 8) atom_feats = relu(afat @ W_vc^T + prev_hid @ W_vv^T)
  mgemm<3><<<dim3(256, 2), 256, 0, stream>>>(
      afh, afl, prev_hid, nullptr, WcvTh, WcvTl, 512,
      nullptr, nullptr, nullptr, nullptr,
      atfh, atfl, N_ATOMS, 256, 512, 256, 256, 0, 1, 0);
  // 9) atom head
  mgemm<1><<<dim3(256, 4), 256, 0, stream>>>(
      atfh, atfl, nullptr, nullptr, A1Th, A1Tl, 256,
      nullptr, nullptr, a1, nullptr,
      t1h, t1l, N_ATOMS, 512, 256, 256, 512, 0, 1, 0);
  mgemm<1><<<dim3(256, 1), 256, 0, stream>>>(
      t1h, t1l, nullptr, nullptr, A2Th, A2Tl, 512,
      nullptr, nullptr, a2, nullptr,
      out, nullptr, N_ATOMS, 128, 512, 512, 0, 0, 0, 2);
  // 10) bond head via linearity: P1 = atomf@B1_top, P2 = atomf@B1_bot
  mgemm<1><<<dim3(256, 4), 256, 0, stream>>>(
      atfh, atfl, nullptr, nullptr, B1Th, B1Tl, 512,
      nullptr, nullptr, nullptr, nullptr,
      P1h, P1l, N_ATOMS, 512, 256, 256, 512, 0, 0, 0);
  mgemm<1><<<dim3(256, 4), 256, 0, stream>>>(
      atfh, atfl, nullptr, nullptr, B1Th + 256, B1Tl + 256, 512,
      nullptr, nullptr, nullptr, nullptr,
      P2h, P2l, N_ATOMS, 512, 256, 256, 512, 0, 0, 0);
  //     out_bond = relu(P1[a0]+P2[a1]+b1) @ B2 + b2b
  mgemm<5><<<dim3(512, 1), 256, 0, stream>>>(
      P1h, P1l, P2h, P2l, B2Th, B2Tl, 512,
      nullptr, nullptr, b2b, b1,
      out, nullptr, N_UND, 32, 512, 0, 0, 0, 0, 3);
  // 11) graph head
  gv_k<<<512, 256, 0, stream>>>(atfh, atfl, gvec);
  gh_k<<<512, 512, 0, stream>>>(gvec, G1, g1, G2, g2, out);
}

// Round 11
// 2387.731 us; speedup vs baseline: 2.1286x; 2.1286x over previous
//
#include <hip/hip_runtime.h>
#include <cstdint>
#include <cstddef>

#define B_MOL 512
#define A_PER 64
#define ED_PER 256
#define N_ATOMS (B_MOL * A_PER)   // 32768
#define N_DIR (B_MOL * ED_PER)    // 131072
#define N_UND (B_MOL * 128)       // 65536
#define HID 256
#define OUT_STRIDE 12289
#define AP 40   // LDS pitch (shorts) for a 32-wide k row (mgemm)
#define CP 72   // combined-plane LDS pitch (shorts): 32 hi | 32 lo | 8 pad

typedef __attribute__((ext_vector_type(8))) short bf16x8;
typedef __attribute__((ext_vector_type(8))) unsigned short u16x8;
typedef __attribute__((ext_vector_type(4))) float f32x4;

#define MFMA(a, b, c) __builtin_amdgcn_mfma_f32_16x16x32_bf16(a, b, c, 0, 0, 0)

__device__ __forceinline__ float b2f(unsigned short s) {
  return __builtin_bit_cast(float, (unsigned)s << 16);
}
// split fp32 -> (hi, lo) bf16 planes: x ~= hi + lo, |err| <~ 2^-16 |x|
__device__ __forceinline__ void split2(float v, unsigned short& h, unsigned short& l) {
  unsigned ub = __builtin_bit_cast(unsigned, v);
  h = (unsigned short)(ub >> 16);
  float fh = __builtin_bit_cast(float, ub & 0xffff0000u);
  float r = v - fh;
  l = (unsigned short)(__builtin_bit_cast(unsigned, r) >> 16);
}
// fp32 -> bf16 round-to-nearest-even (for the fb single plane)
__device__ __forceinline__ unsigned short f2bf_rne(float v) {
  unsigned u = __builtin_bit_cast(unsigned, v);
  u += 0x7FFFu + ((u >> 16) & 1u);
  return (unsigned short)(u >> 16);
}
__device__ __forceinline__ int e_src(int e) {
  return (e < 64) ? e : (e < 128) ? (e - 64)
       : (e < 192) ? ((e - 127) & 63) : ((e - 190) & 63);
}

// ---------------------------------------------------------------------------
// convAll: ALL weight pre-converts in one launch. dst[n][k] split planes.
// Blocks [3232, 7328): f_bonds -> single bf16 (RNE) plane [131072][128].
// ---------------------------------------------------------------------------
__global__ __launch_bounds__(256) void convAll(
    const float* Wi, const float* Wh, const float* Wo,
    const float* Wq, const float* Wk, const float* Wv,
    const float* Wattn, const float* Wvc, const float* Wvv,
    const float* A1, const float* A2, const float* B1, const float* B2,
    const float* fbF, unsigned short* fbT,
    unsigned short* WiTh, unsigned short* WiTl,
    unsigned short* WhTh, unsigned short* WhTl,
    unsigned short* WoTh, unsigned short* WoTl,
    unsigned short* WqkvTh, unsigned short* WqkvTl,
    unsigned short* WaTh, unsigned short* WaTl,
    unsigned short* WcvTh, unsigned short* WcvTl,
    unsigned short* A1Th, unsigned short* A1Tl,
    unsigned short* A2Th, unsigned short* A2Tl,
    unsigned short* B1Th, unsigned short* B1Tl,
    unsigned short* B2Th, unsigned short* B2Tl) {
  int b = blockIdx.x;
  if (b >= 3232) {  // f_bonds convert: 32 edges per block, 8 thr/edge
    int e = (b - 3232) * 32 + (threadIdx.x >> 3);
    int ks = (threadIdx.x & 7) * 16;
    const float* s = fbF + (size_t)e * 111;
    u16x8 o0 = {0,0,0,0,0,0,0,0}, o1 = {0,0,0,0,0,0,0,0};
#pragma unroll
    for (int z = 0; z < 8; ++z) {
      int k = ks + z;
      if (k < 111) o0[z] = f2bf_rne(s[k]);
    }
#pragma unroll
    for (int z = 0; z < 8; ++z) {
      int k = ks + 8 + z;
      if (k < 111) o1[z] = f2bf_rne(s[k]);
    }
    *(u16x8*)&fbT[(size_t)e * 128 + ks] = o0;
    *(u16x8*)&fbT[(size_t)e * 128 + ks + 8] = o1;
    return;
  }
  const float *src = nullptr, *src2 = nullptr;
  unsigned short *dh = nullptr, *dl = nullptr;
  int K = 256, N = 256, Kp = 256, mode = 0, n = 0;
  if (b < 2048) {
    int seg = b >> 8; n = b & 255;
    switch (seg) {
      case 0: src = Wi; dh = WiTh; dl = WiTl; K = 111; Kp = 128; break;
      case 1: src = Wh; dh = WhTh; dl = WhTl; break;
      case 2: src = Wo; dh = WoTh; dl = WoTl; K = 354; Kp = 384; mode = 1; break;
      case 3: src = Wq; dh = WqkvTh; dl = WqkvTl; break;
      case 4: src = Wk; dh = WqkvTh + 65536; dl = WqkvTl + 65536; break;
      case 5: src = Wv; dh = WqkvTh + 131072; dl = WqkvTl + 131072; break;
      case 6: src = Wattn; dh = WaTh; dl = WaTl; break;
      default: src = Wvc; src2 = Wvv; dh = WcvTh; dl = WcvTl; K = 512; Kp = 512; mode = 2; break;
    }
  } else if (b < 2560) { n = b - 2048; src = A1; dh = A1Th; dl = A1Tl; K = 256; N = 512; Kp = 256; }
  else if (b < 2688)   { n = b - 2560; src = A2; dh = A2Th; dl = A2Tl; K = 512; N = 128; Kp = 512; }
  else if (b < 3200)   { n = b - 2688; src = B1; dh = B1Th; dl = B1Tl; K = 512; N = 512; Kp = 512; }
  else                 { n = b - 3200; src = B2; dh = B2Th; dl = B2Tl; K = 512; N = 32;  Kp = 512; }
  for (int k = threadIdx.x; k < Kp; k += 256) {
    float v = 0.f;
    if (mode == 0) { if (k < K) v = src[(size_t)k * N + n]; }
    else if (mode == 1) {
      if (k < 256) v = src[(size_t)(98 + k) * 256 + n];
      else if (k < 354) v = src[(size_t)(k - 256) * 256 + n];
    } else {
      v = (k < 256) ? src[(size_t)n * 256 + k] : src2[(size_t)n * 256 + (k - 256)];
    }
    unsigned short h_, l_;
    split2(v, h_, l_);
    dh[(size_t)n * Kp + k] = h_;
    dl[(size_t)n * Kp + k] = l_;
  }
}

// ---------------------------------------------------------------------------
// mgemm: split-bf16 MFMA GEMM. 128x128 tile, BK=32, 256 thr (4 waves, 2x2),
// 64x64/wave, 3 MFMA per frag-pair (2 for AMODE 6: single-plane A).
// B pre-split/pre-transposed global [N][Kp] planes (BTh/BTl, ldb=Kp).
// AMODE 0: fp32 A [M][lda]; 1: split A planes; 2: concat fp32 asumF|f_atoms;
//       3: split afat | fp32 prev_hid; 5: bond combine relu(P1[a0]+P2[a1]+b);
//       6: SINGLE bf16 plane A [M][lda] (fb), 2 MFMA/frag.
// outmode 0: split planes; 1: fp32 (+outcol); 2: atom-head; 3: bond-head.
// ---------------------------------------------------------------------------
template <int AMODE>
__launch_bounds__(256, 3)
__global__ void mgemm(const void* Aa_, const void* Ab_, const void* Ac_, const void* Ad_,
                      const unsigned short* __restrict__ BTh,
                      const unsigned short* __restrict__ BTl, int ldb,
                      const unsigned short* addH, const unsigned short* addL,
                      const float* __restrict__ bias,
                      const float* __restrict__ abias,
                      void* outA, void* outB,
                      int M, int N, int K, int lda, int ldco, int outcol,
                      int relu, int outmode) {
  __shared__ unsigned short AsH[128 * AP], AsL[128 * AP];
  __shared__ unsigned short BsH[128 * AP], BsL[128 * AP];
  const int tid = threadIdx.x;
  const int lane = tid & 63;
  const int l15 = lane & 15, l4 = lane >> 4;
  const int w = tid >> 6;
  const int wr = (w >> 1) * 64, wc = (w & 1) * 64;
  const int tileM = blockIdx.x * 128, tileN = blockIdx.y * 128;
  const int srow = tid >> 1;           // staging row 0..127
  const int sks = (tid & 1) * 16;      // staging k-seg {0,16}

  int rem = N - tileN - wc;
  int bnMax = rem >= 64 ? 4 : (rem > 0 ? (rem >> 4) : 0);

  f32x4 zf = {0.f, 0.f, 0.f, 0.f};
  f32x4 acc[4][4];
#pragma unroll
  for (int i = 0; i < 4; ++i)
#pragma unroll
    for (int j = 0; j < 4; ++j) acc[i][j] = zf;

  const int nkb = (K + 31) >> 5;
  for (int kb = 0; kb < nkb; ++kb) {
    __syncthreads();
    const int k0 = kb * 32 + sks;
    // ---- stage A ----
    {
      const int row = tileM + srow;
      if (AMODE == 6) {
        const unsigned short* Ah = (const unsigned short*)Aa_;
        size_t bse = (size_t)row * lda + k0;
        *(u16x8*)&AsH[srow * AP + sks]     = *(const u16x8*)&Ah[bse];
        *(u16x8*)&AsH[srow * AP + sks + 8] = *(const u16x8*)&Ah[bse + 8];
      } else if (AMODE == 1 || (AMODE == 3 && k0 < 256)) {
        const unsigned short* Ah = (const unsigned short*)Aa_;
        const unsigned short* Al = (const unsigned short*)Ab_;
        size_t bse = (AMODE == 3) ? ((size_t)row * 256 + k0)
                                  : ((size_t)row * lda + k0);
        *(u16x8*)&AsH[srow * AP + sks]     = *(const u16x8*)&Ah[bse];
        *(u16x8*)&AsH[srow * AP + sks + 8] = *(const u16x8*)&Ah[bse + 8];
        *(u16x8*)&AsL[srow * AP + sks]     = *(const u16x8*)&Al[bse];
        *(u16x8*)&AsL[srow * AP + sks + 8] = *(const u16x8*)&Al[bse + 8];
      } else if (AMODE == 5) {
        int mol = row >> 7, u = row & 127;
        int a0 = (u < 64) ? u : (u - 64);
        int a1v = (u < 64) ? ((u + 1) & 63) : ((u - 62) & 63);
        size_t p1 = (size_t)(mol * 64 + a0) * 512 + k0;
        size_t p2 = (size_t)(mol * 64 + a1v) * 512 + k0;
        const unsigned short* P1h = (const unsigned short*)Aa_;
        const unsigned short* P1l = (const unsigned short*)Ab_;
        const unsigned short* P2h = (const unsigned short*)Ac_;
        const unsigned short* P2l = (const unsigned short*)Ad_;
        u16x8 x1h[2] = {*(const u16x8*)&P1h[p1], *(const u16x8*)&P1h[p1 + 8]};
        u16x8 x1l[2] = {*(const u16x8*)&P1l[p1], *(const u16x8*)&P1l[p1 + 8]};
        u16x8 x2h[2] = {*(const u16x8*)&P2h[p2], *(const u16x8*)&P2h[p2 + 8]};
        u16x8 x2l[2] = {*(const u16x8*)&P2l[p2], *(const u16x8*)&P2l[p2 + 8]};
#pragma unroll
        for (int c = 0; c < 2; ++c) {
          u16x8 hv, lv;
#pragma unroll
          for (int z = 0; z < 8; ++z) {
            float v = b2f(x1h[c][z]) + b2f(x1l[c][z])
                    + b2f(x2h[c][z]) + b2f(x2l[c][z]) + abias[k0 + c * 8 + z];
            v = fmaxf(v, 0.f);
            unsigned short h_, l_;
            split2(v, h_, l_);
            hv[z] = h_; lv[z] = l_;
          }
          *(u16x8*)&AsH[srow * AP + sks + c * 8] = hv;
          *(u16x8*)&AsL[srow * AP + sks + c * 8] = lv;
        }
      } else {
        u16x8 hv0 = {0,0,0,0,0,0,0,0}, lv0 = {0,0,0,0,0,0,0,0};
        u16x8 hv1 = {0,0,0,0,0,0,0,0}, lv1 = {0,0,0,0,0,0,0,0};
#pragma unroll
        for (int z = 0; z < 16; ++z) {
          int k = k0 + z;
          float v = 0.f;
          if (AMODE == 0) {
            if (k < K) v = ((const float*)Aa_)[(size_t)row * lda + k];
          } else if (AMODE == 2) {
            if (k < 256) v = ((const float*)Aa_)[(size_t)row * 256 + k];
            else if (k < 354) v = ((const float*)Ab_)[(size_t)row * 98 + (k - 256)];
          } else {  // AMODE 3, k0 >= 256
            v = ((const float*)Ac_)[(size_t)row * 256 + (k - 256)];
          }
          unsigned short h_, l_;
          split2(v, h_, l_);
          if (z < 8) { hv0[z] = h_; lv0[z] = l_; }
          else       { hv1[z - 8] = h_; lv1[z - 8] = l_; }
        }
        *(u16x8*)&AsH[srow * AP + sks]     = hv0;
        *(u16x8*)&AsH[srow * AP + sks + 8] = hv1;
        *(u16x8*)&AsL[srow * AP + sks]     = lv0;
        *(u16x8*)&AsL[srow * AP + sks + 8] = lv1;
      }
    }
    // ---- stage B ----
    {
      const int n = tileN + srow;
      if (n < N) {
        size_t bb = (size_t)n * ldb + k0;
        *(u16x8*)&BsH[srow * AP + sks]     = *(const u16x8*)&BTh[bb];
        *(u16x8*)&BsH[srow * AP + sks + 8] = *(const u16x8*)&BTh[bb + 8];
        *(u16x8*)&BsL[srow * AP + sks]     = *(const u16x8*)&BTl[bb];
        *(u16x8*)&BsL[srow * AP + sks + 8] = *(const u16x8*)&BTl[bb + 8];
      } else {
        u16x8 z8 = {0,0,0,0,0,0,0,0};
        *(u16x8*)&BsH[srow * AP + sks]     = z8;
        *(u16x8*)&BsH[srow * AP + sks + 8] = z8;
        *(u16x8*)&BsL[srow * AP + sks]     = z8;
        *(u16x8*)&BsL[srow * AP + sks + 8] = z8;
      }
    }
    __syncthreads();
    // ---- compute ----
    bf16x8 ah[4], al[4];
#pragma unroll
    for (int am = 0; am < 4; ++am) {
      int ar = wr + am * 16 + l15;
      ah[am] = *(const bf16x8*)&AsH[ar * AP + l4 * 8];
      if (AMODE != 6) al[am] = *(const bf16x8*)&AsL[ar * AP + l4 * 8];
    }
#pragma unroll
    for (int bn = 0; bn < 4; ++bn) {
      if (bn < bnMax) {
        int br = wc + bn * 16 + l15;
        bf16x8 bh = *(const bf16x8*)&BsH[br * AP + l4 * 8];
        bf16x8 bl = *(const bf16x8*)&BsL[br * AP + l4 * 8];
#pragma unroll
        for (int am = 0; am < 4; ++am) {
          acc[am][bn] = MFMA(ah[am], bh, acc[am][bn]);
          acc[am][bn] = MFMA(ah[am], bl, acc[am][bn]);
          if (AMODE != 6) acc[am][bn] = MFMA(al[am], bh, acc[am][bn]);
        }
      }
    }
  }

  // ---- epilogue ----
#pragma unroll
  for (int am = 0; am < 4; ++am) {
#pragma unroll
    for (int bn = 0; bn < 4; ++bn) {
      if (bn >= bnMax) continue;
      int col = tileN + wc + bn * 16 + l15;
      float bs = bias ? bias[col] : 0.f;
#pragma unroll
      for (int r = 0; r < 4; ++r) {
        size_t row = (size_t)tileM + wr + am * 16 + l4 * 4 + r;
        float v = acc[am][bn][r] + bs;
        if (addH) v += b2f(addH[row * 256 + col]) + b2f(addL[row * 256 + col]);
        if (relu) v = fmaxf(v, 0.f);
        if (outmode == 0) {
          unsigned short h_, l_;
          split2(v, h_, l_);
          ((unsigned short*)outA)[row * (size_t)ldco + col] = h_;
          ((unsigned short*)outB)[row * (size_t)ldco + col] = l_;
        } else if (outmode == 1) {
          ((float*)outA)[row * (size_t)ldco + outcol + col] = v;
        } else if (outmode == 2) {
          int mol = (int)(row >> 6), t = (int)(row & 63);
          ((float*)outA)[(size_t)mol * OUT_STRIDE + 4096 + t * 128 + col] = v;
        } else {
          int mol = (int)(row >> 7), u = (int)(row & 127);
          ((float*)outA)[(size_t)mol * OUT_STRIDE + u * 32 + col] = v;
        }
      }
    }
  }
}

// ---------------------------------------------------------------------------
// msg_f5: PERSISTENT fused DMPNN — all 9 iterations inside one kernel.
// One block per molecule (owns all 256 edges across ALL iterations -> only
// block-local sync needed; zero cross-block data flow). 1024 thr = 16 waves
// (4M x 4N), wave tile 64x64, acc[4][4], BK=32, combined-plane LDS 73,728 B
// (2 blocks/CU). NO agent fence between iterations: producer and consumers
// of each h row are the SAME block (same CU, write-through L1), and
// __syncthreads() guarantees block-wide visibility of prior global writes
// (compiler drains vmcnt before s_barrier). The round-10 __threadfence()
// was an agent-scope L2 writeback/invalidate per iteration — catastrophic.
// ---------------------------------------------------------------------------
__launch_bounds__(1024)
__global__ void msg_f5(float* h,
                       const unsigned short* __restrict__ WhTh,
                       const unsigned short* __restrict__ WhTl,
                       const unsigned short* __restrict__ WiTh,
                       const unsigned short* __restrict__ WiTl,
                       const unsigned short* __restrict__ fbT,
                       int iters) {
  extern __shared__ char smem_[];
  unsigned short* AsC = (unsigned short*)smem_;              // 256*72*2 = 36864 B
  unsigned short* BsC = (unsigned short*)(smem_ + 36864);    // 36864 B
  const int tid = threadIdx.x;
  const int lane = tid & 63, l15 = lane & 15, l4 = lane >> 4;
  const int w = tid >> 6;          // 0..15
  const int wm = (w >> 2) * 64;    // row base: 0,64,128,192
  const int wn = (w & 3) * 64;     // col base: 0,64,128,192
  const int mol = blockIdx.x;
  const int arow = tid >> 2;       // staging row 0..255 (edge id, identity)
  const int aks = (tid & 3) * 8;   // staging k sub-seg {0,8,16,24}

  // per-staged-edge graph indices (block owns whole molecule; edge = arow)
  const int sA = e_src(arow);
  const int rvA = (arow < 128) ? (arow + 128) : (arow - 128);
  const int i0 = (sA + 63) & 63;
  const int i1 = 64 + ((sA + 62) & 63);
  const int i2 = 128 + sA;
  const int i3 = 192 + sA;
  const size_t hbase = (size_t)mol * 256 * 256;
  const size_t fbb = (size_t)(mol * 256 + arow) * 128;

  for (int d = 0; d < iters; ++d) {
    f32x4 acc[4][4];
#pragma unroll
    for (int i = 0; i < 4; ++i)
#pragma unroll
      for (int j = 0; j < 4; ++j) acc[i][j] = (f32x4){0.f, 0.f, 0.f, 0.f};

    // ---- phase 1: acc = fbT @ Wi (K=128 padded -> 4 chunks of 32) ----
    for (int kb = 0; kb < 4; ++kb) {
      __syncthreads();
      {
        *(u16x8*)&AsC[arow * CP + aks] = *(const u16x8*)&fbT[fbb + kb * 32 + aks];
      }
      {
        size_t bb = (size_t)arow * 128 + kb * 32 + aks;  // Wi pitch 128
        *(u16x8*)&BsC[arow * CP + aks]      = *(const u16x8*)&WiTh[bb];
        *(u16x8*)&BsC[arow * CP + 32 + aks] = *(const u16x8*)&WiTl[bb];
      }
      __syncthreads();
      bf16x8 ah[4];
#pragma unroll
      for (int am = 0; am < 4; ++am) {
        int ar = wm + am * 16 + l15;
        ah[am] = *(const bf16x8*)&AsC[ar * CP + l4 * 8];
      }
#pragma unroll
      for (int bn = 0; bn < 4; ++bn) {
        int br = wn + bn * 16 + l15;
        bf16x8 bh = *(const bf16x8*)&BsC[br * CP + l4 * 8];
        bf16x8 bl = *(const bf16x8*)&BsC[br * CP + 32 + l4 * 8];
#pragma unroll
        for (int am = 0; am < 4; ++am) {
          acc[am][bn] = MFMA(ah[am], bh, acc[am][bn]);
          acc[am][bn] = MFMA(ah[am], bl, acc[am][bn]);
        }
      }
    }
    // mid-relu -> acc holds h0
#pragma unroll
    for (int i = 0; i < 4; ++i)
#pragma unroll
      for (int j = 0; j < 4; ++j)
#pragma unroll
        for (int r = 0; r < 4; ++r) acc[i][j][r] = fmaxf(acc[i][j][r], 0.f);

    // ---- phase 2: acc += m @ Wh, K=256 (8 chunks); fused a_sum staging ----
    for (int kb = 0; kb < 8; ++kb) {
      __syncthreads();
      {
        const int c0 = kb * 32 + aks;
        f32x4 m0, m1;
        {
          const float* p = &h[hbase + (size_t)i0 * 256 + c0];
          m0 = *(const f32x4*)p;
          m1 = *(const f32x4*)(p + 4);
        }
        {
          const float* p = &h[hbase + (size_t)i1 * 256 + c0];
          m0 += *(const f32x4*)p;
          m1 += *(const f32x4*)(p + 4);
        }
        {
          const float* p = &h[hbase + (size_t)i2 * 256 + c0];
          m0 += *(const f32x4*)p;
          m1 += *(const f32x4*)(p + 4);
        }
        {
          const float* p = &h[hbase + (size_t)i3 * 256 + c0];
          m0 += *(const f32x4*)p;
          m1 += *(const f32x4*)(p + 4);
        }
        {
          const float* p = &h[hbase + (size_t)rvA * 256 + c0];
          m0 -= *(const f32x4*)p;
          m1 -= *(const f32x4*)(p + 4);
        }
        u16x8 hv, lv;
#pragma unroll
        for (int z = 0; z < 4; ++z) {
          unsigned short h_, l_;
          split2(m0[z], h_, l_); hv[z] = h_; lv[z] = l_;
          split2(m1[z], h_, l_); hv[4 + z] = h_; lv[4 + z] = l_;
        }
        *(u16x8*)&AsC[arow * CP + aks]      = hv;
        *(u16x8*)&AsC[arow * CP + 32 + aks] = lv;
      }
      {
        size_t bb = (size_t)arow * 256 + kb * 32 + aks;  // Wh pitch 256
        *(u16x8*)&BsC[arow * CP + aks]      = *(const u16x8*)&WhTh[bb];
        *(u16x8*)&BsC[arow * CP + 32 + aks] = *(const u16x8*)&WhTl[bb];
      }
      __syncthreads();
      bf16x8 ah[4], al[4];
#pragma unroll
      for (int am = 0; am < 4; ++am) {
        int ar = wm + am * 16 + l15;
        ah[am] = *(const bf16x8*)&AsC[ar * CP + l4 * 8];
        al[am] = *(const bf16x8*)&AsC[ar * CP + 32 + l4 * 8];
      }
#pragma unroll
      for (int bn = 0; bn < 4; ++bn) {
        int br = wn + bn * 16 + l15;
        bf16x8 bh = *(const bf16x8*)&BsC[br * CP + l4 * 8];
        bf16x8 bl = *(const bf16x8*)&BsC[br * CP + 32 + l4 * 8];
#pragma unroll
        for (int am = 0; am < 4; ++am) {
          acc[am][bn] = MFMA(ah[am], bh, acc[am][bn]);
          acc[am][bn] = MFMA(ah[am], bl, acc[am][bn]);
          acc[am][bn] = MFMA(al[am], bh, acc[am][bn]);
        }
      }
    }

    // ---- epilogue: h = relu(acc) fp32, in-place (block owns its rows) ----
#pragma unroll
    for (int am = 0; am < 4; ++am) {
#pragma unroll
      for (int r = 0; r < 4; ++r) {
        int row = wm + am * 16 + l4 * 4 + r;
        size_t rowb = hbase + (size_t)row * 256;
#pragma unroll
        for (int bn = 0; bn < 4; ++bn) {
          int col = wn + bn * 16 + l15;
          h[rowb + col] = fmaxf(acc[am][bn][r], 0.f);
        }
      }
    }
    // Block-scope ordering only (no cache ops). The __syncthreads() at the
    // top of the next iteration's first chunk provides block-wide visibility
    // of these global writes (same CU, write-through L1).
    __threadfence_block();
  }
}

// a_sum over the 4 incoming directed edges of each atom (fp32 h -> fp32 out)
__global__ __launch_bounds__(256) void asum_f(const float* __restrict__ h,
                                              float* __restrict__ out) {
  int g = blockIdx.x * 256 + threadIdx.x;  // 32768 atoms x 32 chunks of 8
  int atom = g >> 5, cc = (g & 31) << 3;
  int mol = atom >> 6, t = atom & 63;
  const float* hb = h + (size_t)mol * ED_PER * HID;
  int e0 = (t + 63) & 63;
  int e1 = 64 + ((t + 62) & 63);
  int e2 = 128 + t;
  int e3 = 192 + t;
  f32x4 s0 = {0.f, 0.f, 0.f, 0.f}, s1 = {0.f, 0.f, 0.f, 0.f};
#define ACC_E(ee) { \
    const float* p = hb + (size_t)(ee) * HID + cc; \
    s0 += *(const f32x4*)p; \
    s1 += *(const f32x4*)(p + 4); }
  ACC_E(e0); ACC_E(e1); ACC_E(e2); ACC_E(e3);
#undef ACC_E
  *(f32x4*)&out[(size_t)atom * HID + cc] = s0;
  *(f32x4*)&out[(size_t)atom * HID + cc + 4] = s1;
}

// flash attention, fp32 qkv in, split ctx out: one wave per (mol, head)
__global__ __launch_bounds__(64) void attn_k(const float* __restrict__ qkv,
                                             unsigned short* __restrict__ ctxH,
                                             unsigned short* __restrict__ ctxL) {
  __shared__ float kls[64 * 32];
  __shared__ float vls[64 * 32];
  int mol = blockIdx.x >> 3, head = blockIdx.x & 7;
  int lane = threadIdx.x;
  size_t rb = ((size_t)(mol * 64 + lane)) * 768 + head * 32;
#pragma unroll
  for (int c = 0; c < 8; ++c) {
    *(float4*)(kls + lane * 32 + c * 4) = *(const float4*)(qkv + rb + 256 + c * 4);
    *(float4*)(vls + lane * 32 + c * 4) = *(const float4*)(qkv + rb + 512 + c * 4);
  }
  float q[32];
#pragma unroll
  for (int d = 0; d < 32; ++d) q[d] = qkv[rb + d];
  __syncthreads();
  float mx = -1e30f, l = 0.f;
  float acc[32];
#pragma unroll
  for (int d = 0; d < 32; ++d) acc[d] = 0.f;
  for (int j = 0; j < 64; ++j) {
    float s = 0.f;
#pragma unroll
    for (int d = 0; d < 32; ++d) s += q[d] * kls[j * 32 + d];
    s *= 0.17677669529663687f;  // 1/sqrt(32)
    float nm = fmaxf(mx, s);
    float co = __expf(mx - nm);
    float p = __expf(s - nm);
    l = l * co + p;
#pragma unroll
    for (int d = 0; d < 32; ++d) acc[d] = acc[d] * co + p * vls[j * 32 + d];
    mx = nm;
  }
  float inv = 1.f / l;
  size_t ob = ((size_t)(mol * 64 + lane)) * 256 + head * 32;
#pragma unroll
  for (int d = 0; d < 32; ++d) {
    unsigned short h_, l_;
    split2(acc[d] * inv, h_, l_);
    ctxH[ob + d] = h_;
    ctxL[ob + d] = l_;
  }
}

// graph_vecs[mol][c] = sum over 64 atoms (split atomf planes)
__global__ __launch_bounds__(256) void gv_k(const unsigned short* __restrict__ afH,
                                            const unsigned short* __restrict__ afL,
                                            float* __restrict__ gv) {
  int mol = blockIdx.x, c = threadIdx.x;
  float s = 0.f;
  for (int a = 0; a < 64; ++a) {
    size_t i = ((size_t)mol * 64 + a) * 256 + c;
    s += b2f(afH[i]) + b2f(afL[i]);
  }
  gv[mol * 256 + c] = s;
}

// graph head: relu(gv@G1+g1)@G2+g2 -> out[mol*12289+12288]
__global__ __launch_bounds__(512) void gh_k(const float* __restrict__ gv, const float* __restrict__ G1,
                                            const float* __restrict__ g1, const float* __restrict__ G2,
                                            const float* __restrict__ g2, float* __restrict__ out) {
  __shared__ float xs[256];
  __shared__ float red[512];
  int mol = blockIdx.x, j = threadIdx.x;
  if (j < 256) xs[j] = gv[mol * 256 + j];
  __syncthreads();
  float s = 0.f;
  for (int k = 0; k < 256; ++k) s += xs[k] * G1[k * 512 + j];
  s = fmaxf(s + g1[j], 0.f);
  red[j] = s * G2[j];
  __syncthreads();
  for (int st = 256; st > 0; st >>= 1) {
    if (j < st) red[j] += red[j + st];
    __syncthreads();
  }
  if (j == 0) out[(size_t)mol * OUT_STRIDE + 12288] = red[0] + g2[0];
}

extern "C" void kernel_launch(void* const* d_in, const int* in_sizes, int n_in,
                              void* d_out, int out_size, void* d_ws, size_t ws_size,
                              hipStream_t stream) {
  (void)in_sizes; (void)n_in; (void)out_size; (void)ws_size;
  const float* f_atoms  = (const float*)d_in[0];
  const float* f_bonds  = (const float*)d_in[1];
  const float* prev_hid = (const float*)d_in[2];
  const float* W_i   = (const float*)d_in[7];
  const float* W_h   = (const float*)d_in[8];
  const float* W_o   = (const float*)d_in[9];
  const float* b_o   = (const float*)d_in[10];
  const float* Wq    = (const float*)d_in[11];
  const float* Wk    = (const float*)d_in[12];
  const float* Wv    = (const float*)d_in[13];
  const float* Wattn = (const float*)d_in[14];
  const float* W_vv  = (const float*)d_in[15];
  const float* W_vc  = (const float*)d_in[16];
  const float* A1    = (const float*)d_in[17];
  const float* a1    = (const float*)d_in[18];
  const float* A2    = (const float*)d_in[19];
  const float* a2    = (const float*)d_in[20];
  const float* B1    = (const float*)d_in[21];
  const float* b1    = (const float*)d_in[22];
  const float* B2    = (const float*)d_in[23];
  const float* b2b   = (const float*)d_in[24];
  const float* G1    = (const float*)d_in[25];
  const float* g1    = (const float*)d_in[26];
  const float* G2    = (const float*)d_in[27];
  const float* g2    = (const float*)d_in[28];
  float* out = (float*)d_out;

  // ---- workspace (~172.6 MB < known-good 187.3) ----
  char* base = (char*)d_ws;
  float* h = (float*)(base);                                   // 134.2 MB fp32
  // [134.2M, 167.8M): dual-purpose 32MB region —
  //   fbT (bf16 [131072][128]) during steps 0-2; asumF (fp32) from step 3 on.
  unsigned short* fbT = (unsigned short*)(base + 134217728);
  float* asumF = (float*)(base + 134217728);
  char* W0 = base + 167772160;                                 // weights ~4.8 MB
  unsigned short* WiTh   = (unsigned short*)(W0);
  unsigned short* WiTl   = (unsigned short*)(W0 + 65536);
  unsigned short* WhTh   = (unsigned short*)(W0 + 131072);
  unsigned short* WhTl   = (unsigned short*)(W0 + 262144);
  unsigned short* WoTh   = (unsigned short*)(W0 + 393216);
  unsigned short* WoTl   = (unsigned short*)(W0 + 589824);
  unsigned short* WqkvTh = (unsigned short*)(W0 + 786432);     // [768][256]
  unsigned short* WqkvTl = (unsigned short*)(W0 + 1179648);
  unsigned short* WaTh   = (unsigned short*)(W0 + 1572864);
  unsigned short* WaTl   = (unsigned short*)(W0 + 1703936);
  unsigned short* WcvTh  = (unsigned short*)(W0 + 1835008);
  unsigned short* WcvTl  = (unsigned short*)(W0 + 2097152);
  unsigned short* A1Th   = (unsigned short*)(W0 + 2359296);
  unsigned short* A1Tl   = (unsigned short*)(W0 + 2621440);
  unsigned short* A2Th   = (unsigned short*)(W0 + 2883584);
  unsigned short* A2Tl   = (unsigned short*)(W0 + 3014656);
  unsigned short* B1Th   = (unsigned short*)(W0 + 3145728);
  unsigned short* B1Tl   = (unsigned short*)(W0 + 3670016);
  unsigned short* B2Th   = (unsigned short*)(W0 + 4194304);
  unsigned short* B2Tl   = (unsigned short*)(W0 + 4227072);
  float* gvec            = (float*)(W0 + 4259840);
  // post-loop aliases (sequential-stream lifetimes audited):
  unsigned short* xAh  = (unsigned short*)(base);              // step 4-7
  unsigned short* xAl  = (unsigned short*)(base + 16777216);
  float* qkv           = (float*)(base + 33554432);            // step 5-6, 100.7 MB
  unsigned short* ctxh = (unsigned short*)(base + 134217728);  // step 6-7 (over asumF)
  unsigned short* ctxl = (unsigned short*)(base + 150994944);
  unsigned short* afh  = (unsigned short*)(base + 33554432);   // step 7-8 (over qkv)
  unsigned short* afl  = (unsigned short*)(base + 50331648);
  unsigned short* atfh = (unsigned short*)(base + 67108864);   // step 8-end
  unsigned short* atfl = (unsigned short*)(base + 83886080);
  unsigned short* t1h  = (unsigned short*)(base);              // step 9
  unsigned short* t1l  = (unsigned short*)(base + 33554432);
  unsigned short* P1h  = (unsigned short*)(base);              // step 10
  unsigned short* P1l  = (unsigned short*)(base + 33554432);
  unsigned short* P2h  = (unsigned short*)(base + 100663296);
  unsigned short* P2l  = (unsigned short*)(base + 134217728);

  // 0) all weight pre-converts + f_bonds bf16 plane in one launch
  convAll<<<7328, 256, 0, stream>>>(
      W_i, W_h, W_o, Wq, Wk, Wv, Wattn, W_vc, W_vv, A1, A2, B1, B2,
      f_bonds, fbT,
      WiTh, WiTl, WhTh, WhTl, WoTh, WoTl, WqkvTh, WqkvTl, WaTh, WaTl,
      WcvTh, WcvTl, A1Th, A1Tl, A2Th, A2Tl, B1Th, B1Tl, B2Th, B2Tl);

  // 1) h = h0 = relu(fbT @ W_i)  (single-plane A, fp32 out)
  mgemm<6><<<dim3(1024, 2), 256, 0, stream>>>(
      fbT, nullptr, nullptr, nullptr, WiTh, WiTl, 128,
      nullptr, nullptr, nullptr, nullptr,
      h, nullptr, N_DIR, 256, 128, 128, 256, 0, 1, 1);

  // 2) DMPNN loop: PERSISTENT — all 9 iterations in one launch, one block
  //    per molecule (block-local sync only; molecules independent)
  msg_f5<<<512, 1024, 73728, stream>>>(h, WhTh, WhTl, WiTh, WiTl, fbT, 9);

  // 3) a_in  (asumF overwrites fbT — fbT dead after the loop)
  asum_f<<<4096, 256, 0, stream>>>(h, asumF);
  // 4) a_feats = relu([asum | f_atoms] @ WoT + b_o)
  mgemm<2><<<dim3(256, 2), 256, 0, stream>>>(
      asumF, f_atoms, nullptr, nullptr, WoTh, WoTl, 384,
      nullptr, nullptr, b_o, nullptr,
      xAh, xAl, N_ATOMS, 256, 354, 0, 256, 0, 1, 0);
  // 5) qkv fused (N=768, fp32 out)
  mgemm<1><<<dim3(256, 6), 256, 0, stream>>>(
      xAh, xAl, nullptr, nullptr, WqkvTh, WqkvTl, 256,
      nullptr, nullptr, nullptr, nullptr,
      qkv, nullptr, N_ATOMS, 768, 256, 256, 768, 0, 0, 1);
  // 6) attention
  attn_k<<<4096, 64, 0, stream>>>(qkv, ctxh, ctxl);
  // 7) a_feats' = x + ctx @ Wattn   (addend = xA split)
  mgemm<1><<<dim3(256, 2), 256, 0, stream>>>(
      ctxh, ctxl, nullptr, nullptr, WaTh, WaTl, 256,
      xAh, xAl, nullptr, nullptr,
      afh, afl, N_ATOMS, 256, 256, 256, 256, 0, 0, 0);
  // 8) atom_feats = relu(afat @ W_vc^T + prev_hid @ W_vv^T)
  mgemm<3><<<dim3(256, 2), 256, 0, stream>>>(
      afh, afl, prev_hid, nullptr, WcvTh, WcvTl, 512,
      nullptr, nullptr, nullptr, nullptr,
      atfh, atfl, N_ATOMS, 256, 512, 256, 256, 0, 1, 0);
  // 9) atom head
  mgemm<1><<<dim3(256, 4), 256, 0, stream>>>(
      atfh, atfl, nullptr, nullptr, A1Th, A1Tl, 256,
      nullptr, nullptr, a1, nullptr,
      t1h, t1l, N_ATOMS, 512, 256, 256, 512, 0, 1, 0);
  mgemm<1><<<dim3(256, 1), 256, 0, stream>>>(
      t1h, t1l, nullptr, nullptr, A2Th, A2Tl, 512,
      nullptr, nullptr, a2, nullptr,
      out, nullptr, N_ATOMS, 128, 512, 512, 0, 0, 0, 2);
  // 10) bond head via linearity: P1 = atomf@B1_top, P2 = atomf@B1_bot
  mgemm<1><<<dim3(256, 4), 256, 0, stream>>>(
      atfh, atfl, nullptr, nullptr, B1Th, B1Tl, 512,
      nullptr, nullptr, nullptr, nullptr,
      P1h, P1l, N_ATOMS, 512, 256, 256, 512, 0, 0, 0);
  mgemm<1><<<dim3(256, 4), 256, 0, stream>>>(
      atfh, atfl, nullptr, nullptr, B1Th + 256, B1Tl + 256, 512,
      nullptr, nullptr, nullptr, nullptr,
      P2h, P2l, N_ATOMS, 512, 256, 256, 512, 0, 0, 0);
  //     out_bond = relu(P1[a0]+P2[a1]+b1) @ B2 + b2b
  mgemm<5><<<dim3(512, 1), 256, 0, stream>>>(
      P1h, P1l, P2h, P2l, B2Th, B2Tl, 512,
      nullptr, nullptr, b2b, b1,
      out, nullptr, N_UND, 32, 512, 0, 0, 0, 0, 3);
  // 11) graph head
  gv_k<<<512, 256, 0, stream>>>(atfh, atfl, gvec);
  gh_k<<<512, 512, 0, stream>>>(gvec, G1, g1, G2, g2, out);
}

// Round 12
// 1732.415 us; speedup vs baseline: 2.9338x; 1.3783x over previous
//
#include <hip/hip_runtime.h>
#include <cstdint>
#include <cstddef>

#define B_MOL 512
#define A_PER 64
#define ED_PER 256
#define N_ATOMS (B_MOL * A_PER)   // 32768
#define N_DIR (B_MOL * ED_PER)    // 131072
#define N_UND (B_MOL * 128)       // 65536
#define HID 256
#define OUT_STRIDE 12289
#define AP 40   // LDS pitch (shorts) for a 32-wide k row (mgemm)
#define CP 72   // combined-plane LDS pitch (shorts): 32 hi | 32 lo | 8 pad

typedef __attribute__((ext_vector_type(8))) short bf16x8;
typedef __attribute__((ext_vector_type(8))) unsigned short u16x8;
typedef __attribute__((ext_vector_type(4))) float f32x4;

#define MFMA(a, b, c) __builtin_amdgcn_mfma_f32_16x16x32_bf16(a, b, c, 0, 0, 0)

__device__ __forceinline__ float b2f(unsigned short s) {
  return __builtin_bit_cast(float, (unsigned)s << 16);
}
// split fp32 -> (hi, lo) bf16 planes: x ~= hi + lo, |err| <~ 2^-16 |x|
__device__ __forceinline__ void split2(float v, unsigned short& h, unsigned short& l) {
  unsigned ub = __builtin_bit_cast(unsigned, v);
  h = (unsigned short)(ub >> 16);
  float fh = __builtin_bit_cast(float, ub & 0xffff0000u);
  float r = v - fh;
  l = (unsigned short)(__builtin_bit_cast(unsigned, r) >> 16);
}
// fp32 -> bf16 round-to-nearest-even (for the fb single plane)
__device__ __forceinline__ unsigned short f2bf_rne(float v) {
  unsigned u = __builtin_bit_cast(unsigned, v);
  u += 0x7FFFu + ((u >> 16) & 1u);
  return (unsigned short)(u >> 16);
}
__device__ __forceinline__ int e_src(int e) {
  return (e < 64) ? e : (e < 128) ? (e - 64)
       : (e < 192) ? ((e - 127) & 63) : ((e - 190) & 63);
}

// ---------------------------------------------------------------------------
// convAll: ALL weight pre-converts in one launch. dst[n][k] split planes.
// Block map: [0,2048) 8 segs of 256 (Wi, Wh, Wo, Wq, Wk, Wv, Wattn, Wcv2);
// [2048,2560) A1; [2560,2688) A2; [2688,3712) B1b (N=1024 remap);
// [3712,3744) B2; [3744,7840) f_bonds -> bf16 RNE plane [131072][128].
// seg 7 (Wcv2, Kp=768): k<256 -> Wac[k][n]=dot(Wattn[k][:],Wvc[n][:]);
//   256..512 -> Wvc[n][k-256]; 512..768 -> Wvv[n][k-512].
// B1b [1024][256]: n<512 -> B1[k][n]; n>=512 -> B1[k+256][n-512].
// ---------------------------------------------------------------------------
__global__ __launch_bounds__(256) void convAll(
    const float* Wi, const float* Wh, const float* Wo,
    const float* Wq, const float* Wk, const float* Wv,
    const float* Wattn, const float* Wvc, const float* Wvv,
    const float* A1, const float* A2, const float* B1, const float* B2,
    const float* fbF, unsigned short* fbT,
    unsigned short* WiTh, unsigned short* WiTl,
    unsigned short* WhTh, unsigned short* WhTl,
    unsigned short* WoTh, unsigned short* WoTl,
    unsigned short* WqkvTh, unsigned short* WqkvTl,
    unsigned short* WaTh, unsigned short* WaTl,
    unsigned short* Wcv2Th, unsigned short* Wcv2Tl,
    unsigned short* A1Th, unsigned short* A1Tl,
    unsigned short* A2Th, unsigned short* A2Tl,
    unsigned short* B1bTh, unsigned short* B1bTl,
    unsigned short* B2Th, unsigned short* B2Tl) {
  int b = blockIdx.x;
  if (b >= 3744) {  // f_bonds convert: 32 edges per block, 8 thr/edge
    int e = (b - 3744) * 32 + (threadIdx.x >> 3);
    int ks = (threadIdx.x & 7) * 16;
    const float* s = fbF + (size_t)e * 111;
    u16x8 o0 = {0,0,0,0,0,0,0,0}, o1 = {0,0,0,0,0,0,0,0};
#pragma unroll
    for (int z = 0; z < 8; ++z) {
      int k = ks + z;
      if (k < 111) o0[z] = f2bf_rne(s[k]);
    }
#pragma unroll
    for (int z = 0; z < 8; ++z) {
      int k = ks + 8 + z;
      if (k < 111) o1[z] = f2bf_rne(s[k]);
    }
    *(u16x8*)&fbT[(size_t)e * 128 + ks] = o0;
    *(u16x8*)&fbT[(size_t)e * 128 + ks + 8] = o1;
    return;
  }
  if (b >= 1792 && b < 2048) {  // seg 7: Wcv2 combined [256][768]
    int n = b & 255;
    for (int k = threadIdx.x; k < 768; k += 256) {
      float v;
      if (k < 256) {
        v = 0.f;
        for (int j = 0; j < 256; ++j)
          v += Wattn[(size_t)k * 256 + j] * Wvc[(size_t)n * 256 + j];
      } else if (k < 512) {
        v = Wvc[(size_t)n * 256 + (k - 256)];
      } else {
        v = Wvv[(size_t)n * 256 + (k - 512)];
      }
      unsigned short h_, l_;
      split2(v, h_, l_);
      Wcv2Th[(size_t)n * 768 + k] = h_;
      Wcv2Tl[(size_t)n * 768 + k] = l_;
    }
    return;
  }
  if (b >= 2688 && b < 3712) {  // B1b remap [1024][256]
    int n = b - 2688;
    int k = threadIdx.x;  // 0..255
    float v = (n < 512) ? B1[(size_t)k * 512 + n]
                        : B1[(size_t)(k + 256) * 512 + (n - 512)];
    unsigned short h_, l_;
    split2(v, h_, l_);
    B1bTh[(size_t)n * 256 + k] = h_;
    B1bTl[(size_t)n * 256 + k] = l_;
    return;
  }
  const float* src = nullptr;
  unsigned short *dh = nullptr, *dl = nullptr;
  int K = 256, N = 256, Kp = 256, n = 0;
  if (b < 1792) {
    int seg = b >> 8; n = b & 255;
    switch (seg) {
      case 0: src = Wi; dh = WiTh; dl = WiTl; K = 111; Kp = 128; break;
      case 1: src = Wh; dh = WhTh; dl = WhTl; break;
      case 2: src = Wo; dh = WoTh; dl = WoTl; K = 354; Kp = 384; break;
      case 3: src = Wq; dh = WqkvTh; dl = WqkvTl; break;
      case 4: src = Wk; dh = WqkvTh + 65536; dl = WqkvTl + 65536; break;
      case 5: src = Wv; dh = WqkvTh + 131072; dl = WqkvTl + 131072; break;
      default: src = Wattn; dh = WaTh; dl = WaTl; break;  // seg 6 (kept)
    }
    // seg 2 (Wo) uses remapped rows; others plain transpose
    for (int k = threadIdx.x; k < Kp; k += 256) {
      float v = 0.f;
      if (b >> 8 == 2) {
        if (k < 256) v = src[(size_t)(98 + k) * 256 + n];
        else if (k < 354) v = src[(size_t)(k - 256) * 256 + n];
      } else {
        if (k < K) v = src[(size_t)k * N + n];
      }
      unsigned short h_, l_;
      split2(v, h_, l_);
      dh[(size_t)n * Kp + k] = h_;
      dl[(size_t)n * Kp + k] = l_;
    }
    return;
  }
  if (b < 2560)      { n = b - 2048; src = A1; dh = A1Th; dl = A1Tl; K = 256; N = 512; Kp = 256; }
  else if (b < 2688) { n = b - 2560; src = A2; dh = A2Th; dl = A2Tl; K = 512; N = 128; Kp = 512; }
  else               { n = b - 3712; src = B2; dh = B2Th; dl = B2Tl; K = 512; N = 32;  Kp = 512; }
  for (int k = threadIdx.x; k < Kp; k += 256) {
    float v = (k < K) ? src[(size_t)k * N + n] : 0.f;
    unsigned short h_, l_;
    split2(v, h_, l_);
    dh[(size_t)n * Kp + k] = h_;
    dl[(size_t)n * Kp + k] = l_;
  }
}

// ---------------------------------------------------------------------------
// mgemm: split-bf16 MFMA GEMM. 128x128 tile, BK=32, 256 thr (4 waves, 2x2),
// 64x64/wave, 3 MFMA per frag-pair (2 for AMODE 6).
// B pre-split/pre-transposed global [N][Kp] planes (BTh/BTl, ldb=Kp).
// AMODE 0: fp32 A [M][lda]; 1: split A planes; 2: concat fp32 asumF|f_atoms;
//       5: bond combine relu(P[a0][k]+P[a1][512+k]+b), unified P (Aa/Ab);
//       6: SINGLE bf16 plane A (fb), 2 MFMA/frag;
//       7: triple concat: k<256 ctx(Aa/Ab), k<512 xA(Ac/Ad), k>=512 Af32.
// outmode 0: split planes; 1: fp32 (+outcol); 2: atom-head; 3: bond-head.
// ---------------------------------------------------------------------------
template <int AMODE>
__launch_bounds__(256, 3)
__global__ void mgemm(const void* Aa_, const void* Ab_, const void* Ac_, const void* Ad_,
                      const float* __restrict__ Af32,
                      const unsigned short* __restrict__ BTh,
                      const unsigned short* __restrict__ BTl, int ldb,
                      const unsigned short* addH, const unsigned short* addL,
                      const float* __restrict__ bias,
                      const float* __restrict__ abias,
                      void* outA, void* outB,
                      int M, int N, int K, int lda, int ldco, int outcol,
                      int relu, int outmode) {
  __shared__ unsigned short AsH[128 * AP], AsL[128 * AP];
  __shared__ unsigned short BsH[128 * AP], BsL[128 * AP];
  const int tid = threadIdx.x;
  const int lane = tid & 63;
  const int l15 = lane & 15, l4 = lane >> 4;
  const int w = tid >> 6;
  const int wr = (w >> 1) * 64, wc = (w & 1) * 64;
  const int tileM = blockIdx.x * 128, tileN = blockIdx.y * 128;
  const int srow = tid >> 1;           // staging row 0..127
  const int sks = (tid & 1) * 16;      // staging k-seg {0,16}

  int rem = N - tileN - wc;
  int bnMax = rem >= 64 ? 4 : (rem > 0 ? (rem >> 4) : 0);

  f32x4 zf = {0.f, 0.f, 0.f, 0.f};
  f32x4 acc[4][4];
#pragma unroll
  for (int i = 0; i < 4; ++i)
#pragma unroll
    for (int j = 0; j < 4; ++j) acc[i][j] = zf;

  const int nkb = (K + 31) >> 5;
  for (int kb = 0; kb < nkb; ++kb) {
    __syncthreads();
    const int k0 = kb * 32 + sks;
    // ---- stage A ----
    {
      const int row = tileM + srow;
      if (AMODE == 6) {
        const unsigned short* Ah = (const unsigned short*)Aa_;
        size_t bse = (size_t)row * lda + k0;
        *(u16x8*)&AsH[srow * AP + sks]     = *(const u16x8*)&Ah[bse];
        *(u16x8*)&AsH[srow * AP + sks + 8] = *(const u16x8*)&Ah[bse + 8];
      } else if (AMODE == 1 || (AMODE == 7 && k0 < 512)) {
        const unsigned short* Ah; const unsigned short* Al;
        size_t bse;
        if (AMODE == 7) {
          Ah = (k0 < 256) ? (const unsigned short*)Aa_ : (const unsigned short*)Ac_;
          Al = (k0 < 256) ? (const unsigned short*)Ab_ : (const unsigned short*)Ad_;
          bse = (size_t)row * 256 + (k0 & 255);
        } else {
          Ah = (const unsigned short*)Aa_;
          Al = (const unsigned short*)Ab_;
          bse = (size_t)row * lda + k0;
        }
        *(u16x8*)&AsH[srow * AP + sks]     = *(const u16x8*)&Ah[bse];
        *(u16x8*)&AsH[srow * AP + sks + 8] = *(const u16x8*)&Ah[bse + 8];
        *(u16x8*)&AsL[srow * AP + sks]     = *(const u16x8*)&Al[bse];
        *(u16x8*)&AsL[srow * AP + sks + 8] = *(const u16x8*)&Al[bse + 8];
      } else if (AMODE == 5) {
        int mol = row >> 7, u = row & 127;
        int a0 = (u < 64) ? u : (u - 64);
        int a1v = (u < 64) ? ((u + 1) & 63) : ((u - 62) & 63);
        size_t p1 = (size_t)(mol * 64 + a0) * 1024 + k0;
        size_t p2 = (size_t)(mol * 64 + a1v) * 1024 + 512 + k0;
        const unsigned short* Ph = (const unsigned short*)Aa_;
        const unsigned short* Pl = (const unsigned short*)Ab_;
        u16x8 x1h[2] = {*(const u16x8*)&Ph[p1], *(const u16x8*)&Ph[p1 + 8]};
        u16x8 x1l[2] = {*(const u16x8*)&Pl[p1], *(const u16x8*)&Pl[p1 + 8]};
        u16x8 x2h[2] = {*(const u16x8*)&Ph[p2], *(const u16x8*)&Ph[p2 + 8]};
        u16x8 x2l[2] = {*(const u16x8*)&Pl[p2], *(const u16x8*)&Pl[p2 + 8]};
#pragma unroll
        for (int c = 0; c < 2; ++c) {
          u16x8 hv, lv;
#pragma unroll
          for (int z = 0; z < 8; ++z) {
            float v = b2f(x1h[c][z]) + b2f(x1l[c][z])
                    + b2f(x2h[c][z]) + b2f(x2l[c][z]) + abias[k0 + c * 8 + z];
            v = fmaxf(v, 0.f);
            unsigned short h_, l_;
            split2(v, h_, l_);
            hv[z] = h_; lv[z] = l_;
          }
          *(u16x8*)&AsH[srow * AP + sks + c * 8] = hv;
          *(u16x8*)&AsL[srow * AP + sks + c * 8] = lv;
        }
      } else {
        u16x8 hv0 = {0,0,0,0,0,0,0,0}, lv0 = {0,0,0,0,0,0,0,0};
        u16x8 hv1 = {0,0,0,0,0,0,0,0}, lv1 = {0,0,0,0,0,0,0,0};
#pragma unroll
        for (int z = 0; z < 16; ++z) {
          int k = k0 + z;
          float v = 0.f;
          if (AMODE == 0) {
            if (k < K) v = ((const float*)Aa_)[(size_t)row * lda + k];
          } else if (AMODE == 2) {
            if (k < 256) v = ((const float*)Aa_)[(size_t)row * 256 + k];
            else if (k < 354) v = ((const float*)Ab_)[(size_t)row * 98 + (k - 256)];
          } else {  // AMODE 7, k0 >= 512: prev_hid fp32
            v = Af32[(size_t)row * 256 + (k - 512)];
          }
          unsigned short h_, l_;
          split2(v, h_, l_);
          if (z < 8) { hv0[z] = h_; lv0[z] = l_; }
          else       { hv1[z - 8] = h_; lv1[z - 8] = l_; }
        }
        *(u16x8*)&AsH[srow * AP + sks]     = hv0;
        *(u16x8*)&AsH[srow * AP + sks + 8] = hv1;
        *(u16x8*)&AsL[srow * AP + sks]     = lv0;
        *(u16x8*)&AsL[srow * AP + sks + 8] = lv1;
      }
    }
    // ---- stage B ----
    {
      const int n = tileN + srow;
      if (n < N) {
        size_t bb = (size_t)n * ldb + k0;
        *(u16x8*)&BsH[srow * AP + sks]     = *(const u16x8*)&BTh[bb];
        *(u16x8*)&BsH[srow * AP + sks + 8] = *(const u16x8*)&BTh[bb + 8];
        *(u16x8*)&BsL[srow * AP + sks]     = *(const u16x8*)&BTl[bb];
        *(u16x8*)&BsL[srow * AP + sks + 8] = *(const u16x8*)&BTl[bb + 8];
      } else {
        u16x8 z8 = {0,0,0,0,0,0,0,0};
        *(u16x8*)&BsH[srow * AP + sks]     = z8;
        *(u16x8*)&BsH[srow * AP + sks + 8] = z8;
        *(u16x8*)&BsL[srow * AP + sks]     = z8;
        *(u16x8*)&BsL[srow * AP + sks + 8] = z8;
      }
    }
    __syncthreads();
    // ---- compute ----
    bf16x8 ah[4], al[4];
#pragma unroll
    for (int am = 0; am < 4; ++am) {
      int ar = wr + am * 16 + l15;
      ah[am] = *(const bf16x8*)&AsH[ar * AP + l4 * 8];
      if (AMODE != 6) al[am] = *(const bf16x8*)&AsL[ar * AP + l4 * 8];
    }
#pragma unroll
    for (int bn = 0; bn < 4; ++bn) {
      if (bn < bnMax) {
        int br = wc + bn * 16 + l15;
        bf16x8 bh = *(const bf16x8*)&BsH[br * AP + l4 * 8];
        bf16x8 bl = *(const bf16x8*)&BsL[br * AP + l4 * 8];
#pragma unroll
        for (int am = 0; am < 4; ++am) {
          acc[am][bn] = MFMA(ah[am], bh, acc[am][bn]);
          acc[am][bn] = MFMA(ah[am], bl, acc[am][bn]);
          if (AMODE != 6) acc[am][bn] = MFMA(al[am], bh, acc[am][bn]);
        }
      }
    }
  }

  // ---- epilogue ----
#pragma unroll
  for (int am = 0; am < 4; ++am) {
#pragma unroll
    for (int bn = 0; bn < 4; ++bn) {
      if (bn >= bnMax) continue;
      int col = tileN + wc + bn * 16 + l15;
      float bs = bias ? bias[col] : 0.f;
#pragma unroll
      for (int r = 0; r < 4; ++r) {
        size_t row = (size_t)tileM + wr + am * 16 + l4 * 4 + r;
        float v = acc[am][bn][r] + bs;
        if (addH) v += b2f(addH[row * 256 + col]) + b2f(addL[row * 256 + col]);
        if (relu) v = fmaxf(v, 0.f);
        if (outmode == 0) {
          unsigned short h_, l_;
          split2(v, h_, l_);
          ((unsigned short*)outA)[row * (size_t)ldco + col] = h_;
          ((unsigned short*)outB)[row * (size_t)ldco + col] = l_;
        } else if (outmode == 1) {
          ((float*)outA)[row * (size_t)ldco + outcol + col] = v;
        } else if (outmode == 2) {
          int mol = (int)(row >> 6), t = (int)(row & 63);
          ((float*)outA)[(size_t)mol * OUT_STRIDE + 4096 + t * 128 + col] = v;
        } else {
          int mol = (int)(row >> 7), u = (int)(row & 127);
          ((float*)outA)[(size_t)mol * OUT_STRIDE + u * 32 + col] = v;
        }
      }
    }
  }
}

// ---------------------------------------------------------------------------
// msg_f4: fused DMPNN iteration (round-9 proven), fp32 h, combined-plane LDS
// (73,728 B -> 2 blocks/CU). ONE BLOCK PER MOLECULE. 1024 thr = 16 waves
// (4M x 4N), wave tile 64x64, acc[4][4], BK=32. Multi-launch (one iteration
// per dispatch): the launch boundary is the proven, fastest sync/re-warm.
// ---------------------------------------------------------------------------
__launch_bounds__(1024)
__global__ void msg_f4(float* h,
                       const unsigned short* __restrict__ WhTh,
                       const unsigned short* __restrict__ WhTl,
                       const unsigned short* __restrict__ WiTh,
                       const unsigned short* __restrict__ WiTl,
                       const unsigned short* __restrict__ fbT) {
  extern __shared__ char smem_[];
  unsigned short* AsC = (unsigned short*)smem_;              // 256*72*2 = 36864 B
  unsigned short* BsC = (unsigned short*)(smem_ + 36864);    // 36864 B
  const int tid = threadIdx.x;
  const int lane = tid & 63, l15 = lane & 15, l4 = lane >> 4;
  const int w = tid >> 6;          // 0..15
  const int wm = (w >> 2) * 64;    // row base: 0,64,128,192
  const int wn = (w & 3) * 64;     // col base: 0,64,128,192
  const int mol = blockIdx.x;
  const int arow = tid >> 2;       // staging row 0..255 (edge id, identity)
  const int aks = (tid & 3) * 8;   // staging k sub-seg {0,8,16,24}

  f32x4 acc[4][4];
#pragma unroll
  for (int i = 0; i < 4; ++i)
#pragma unroll
    for (int j = 0; j < 4; ++j) acc[i][j] = (f32x4){0.f, 0.f, 0.f, 0.f};

  const int sA = e_src(arow);
  const int rvA = (arow < 128) ? (arow + 128) : (arow - 128);
  const int i0 = (sA + 63) & 63;
  const int i1 = 64 + ((sA + 62) & 63);
  const int i2 = 128 + sA;
  const int i3 = 192 + sA;
  const size_t hbase = (size_t)mol * 256 * 256;

  // ---- phase 1: acc = fbT @ Wi (K=128 padded -> 4 chunks of 32) ----
  const size_t fbb = (size_t)(mol * 256 + arow) * 128;
  for (int kb = 0; kb < 4; ++kb) {
    __syncthreads();
    {
      *(u16x8*)&AsC[arow * CP + aks] = *(const u16x8*)&fbT[fbb + kb * 32 + aks];
    }
    {
      size_t bb = (size_t)arow * 128 + kb * 32 + aks;  // Wi pitch 128
      *(u16x8*)&BsC[arow * CP + aks]      = *(const u16x8*)&WiTh[bb];
      *(u16x8*)&BsC[arow * CP + 32 + aks] = *(const u16x8*)&WiTl[bb];
    }
    __syncthreads();
    bf16x8 ah[4];
#pragma unroll
    for (int am = 0; am < 4; ++am) {
      int ar = wm + am * 16 + l15;
      ah[am] = *(const bf16x8*)&AsC[ar * CP + l4 * 8];
    }
#pragma unroll
    for (int bn = 0; bn < 4; ++bn) {
      int br = wn + bn * 16 + l15;
      bf16x8 bh = *(const bf16x8*)&BsC[br * CP + l4 * 8];
      bf16x8 bl = *(const bf16x8*)&BsC[br * CP + 32 + l4 * 8];
#pragma unroll
      for (int am = 0; am < 4; ++am) {
        acc[am][bn] = MFMA(ah[am], bh, acc[am][bn]);
        acc[am][bn] = MFMA(ah[am], bl, acc[am][bn]);
      }
    }
  }
  // mid-relu -> acc holds h0
#pragma unroll
  for (int i = 0; i < 4; ++i)
#pragma unroll
    for (int j = 0; j < 4; ++j)
#pragma unroll
      for (int r = 0; r < 4; ++r) acc[i][j][r] = fmaxf(acc[i][j][r], 0.f);

  // ---- phase 2: acc += m @ Wh, K=256 (8 chunks); fused a_sum staging ----
  for (int kb = 0; kb < 8; ++kb) {
    __syncthreads();
    {
      const int c0 = kb * 32 + aks;
      f32x4 m0, m1;
      {
        const float* p = &h[hbase + (size_t)i0 * 256 + c0];
        m0 = *(const f32x4*)p;
        m1 = *(const f32x4*)(p + 4);
      }
      {
        const float* p = &h[hbase + (size_t)i1 * 256 + c0];
        m0 += *(const f32x4*)p;
        m1 += *(const f32x4*)(p + 4);
      }
      {
        const float* p = &h[hbase + (size_t)i2 * 256 + c0];
        m0 += *(const f32x4*)p;
        m1 += *(const f32x4*)(p + 4);
      }
      {
        const float* p = &h[hbase + (size_t)i3 * 256 + c0];
        m0 += *(const f32x4*)p;
        m1 += *(const f32x4*)(p + 4);
      }
      {
        const float* p = &h[hbase + (size_t)rvA * 256 + c0];
        m0 -= *(const f32x4*)p;
        m1 -= *(const f32x4*)(p + 4);
      }
      u16x8 hv, lv;
#pragma unroll
      for (int z = 0; z < 4; ++z) {
        unsigned short h_, l_;
        split2(m0[z], h_, l_); hv[z] = h_; lv[z] = l_;
        split2(m1[z], h_, l_); hv[4 + z] = h_; lv[4 + z] = l_;
      }
      *(u16x8*)&AsC[arow * CP + aks]      = hv;
      *(u16x8*)&AsC[arow * CP + 32 + aks] = lv;
    }
    {
      size_t bb = (size_t)arow * 256 + kb * 32 + aks;  // Wh pitch 256
      *(u16x8*)&BsC[arow * CP + aks]      = *(const u16x8*)&WhTh[bb];
      *(u16x8*)&BsC[arow * CP + 32 + aks] = *(const u16x8*)&WhTl[bb];
    }
    __syncthreads();
    bf16x8 ah[4], al[4];
#pragma unroll
    for (int am = 0; am < 4; ++am) {
      int ar = wm + am * 16 + l15;
      ah[am] = *(const bf16x8*)&AsC[ar * CP + l4 * 8];
      al[am] = *(const bf16x8*)&AsC[ar * CP + 32 + l4 * 8];
    }
#pragma unroll
    for (int bn = 0; bn < 4; ++bn) {
      int br = wn + bn * 16 + l15;
      bf16x8 bh = *(const bf16x8*)&BsC[br * CP + l4 * 8];
      bf16x8 bl = *(const bf16x8*)&BsC[br * CP + 32 + l4 * 8];
#pragma unroll
      for (int am = 0; am < 4; ++am) {
        acc[am][bn] = MFMA(ah[am], bh, acc[am][bn]);
        acc[am][bn] = MFMA(ah[am], bl, acc[am][bn]);
        acc[am][bn] = MFMA(al[am], bh, acc[am][bn]);
      }
    }
  }

  // ---- epilogue: h = relu(acc) fp32, in-place (block owns its rows) ----
#pragma unroll
  for (int am = 0; am < 4; ++am) {
#pragma unroll
    for (int r = 0; r < 4; ++r) {
      int row = wm + am * 16 + l4 * 4 + r;
      size_t rowb = hbase + (size_t)row * 256;
#pragma unroll
      for (int bn = 0; bn < 4; ++bn) {
        int col = wn + bn * 16 + l15;
        h[rowb + col] = fmaxf(acc[am][bn][r], 0.f);
      }
    }
  }
}

// a_sum over the 4 incoming directed edges of each atom (fp32 h -> fp32 out)
__global__ __launch_bounds__(256) void asum_f(const float* __restrict__ h,
                                              float* __restrict__ out) {
  int g = blockIdx.x * 256 + threadIdx.x;  // 32768 atoms x 32 chunks of 8
  int atom = g >> 5, cc = (g & 31) << 3;
  int mol = atom >> 6, t = atom & 63;
  const float* hb = h + (size_t)mol * ED_PER * HID;
  int e0 = (t + 63) & 63;
  int e1 = 64 + ((t + 62) & 63);
  int e2 = 128 + t;
  int e3 = 192 + t;
  f32x4 s0 = {0.f, 0.f, 0.f, 0.f}, s1 = {0.f, 0.f, 0.f, 0.f};
#define ACC_E(ee) { \
    const float* p = hb + (size_t)(ee) * HID + cc; \
    s0 += *(const f32x4*)p; \
    s1 += *(const f32x4*)(p + 4); }
  ACC_E(e0); ACC_E(e1); ACC_E(e2); ACC_E(e3);
#undef ACC_E
  *(f32x4*)&out[(size_t)atom * HID + cc] = s0;
  *(f32x4*)&out[(size_t)atom * HID + cc + 4] = s1;
}

// flash attention, fp32 qkv in, split ctx out: one wave per (mol, head)
__global__ __launch_bounds__(64) void attn_k(const float* __restrict__ qkv,
                                             unsigned short* __restrict__ ctxH,
                                             unsigned short* __restrict__ ctxL) {
  __shared__ float kls[64 * 32];
  __shared__ float vls[64 * 32];
  int mol = blockIdx.x >> 3, head = blockIdx.x & 7;
  int lane = threadIdx.x;
  size_t rb = ((size_t)(mol * 64 + lane)) * 768 + head * 32;
#pragma unroll
  for (int c = 0; c < 8; ++c) {
    *(float4*)(kls + lane * 32 + c * 4) = *(const float4*)(qkv + rb + 256 + c * 4);
    *(float4*)(vls + lane * 32 + c * 4) = *(const float4*)(qkv + rb + 512 + c * 4);
  }
  float q[32];
#pragma unroll
  for (int d = 0; d < 32; ++d) q[d] = qkv[rb + d];
  __syncthreads();
  float mx = -1e30f, l = 0.f;
  float acc[32];
#pragma unroll
  for (int d = 0; d < 32; ++d) acc[d] = 0.f;
  for (int j = 0; j < 64; ++j) {
    float s = 0.f;
#pragma unroll
    for (int d = 0; d < 32; ++d) s += q[d] * kls[j * 32 + d];
    s *= 0.17677669529663687f;  // 1/sqrt(32)
    float nm = fmaxf(mx, s);
    float co = __expf(mx - nm);
    float p = __expf(s - nm);
    l = l * co + p;
#pragma unroll
    for (int d = 0; d < 32; ++d) acc[d] = acc[d] * co + p * vls[j * 32 + d];
    mx = nm;
  }
  float inv = 1.f / l;
  size_t ob = ((size_t)(mol * 64 + lane)) * 256 + head * 32;
#pragma unroll
  for (int d = 0; d < 32; ++d) {
    unsigned short h_, l_;
    split2(acc[d] * inv, h_, l_);
    ctxH[ob + d] = h_;
    ctxL[ob + d] = l_;
  }
}

// graph_vecs[mol][c] = sum over 64 atoms (split atomf planes)
__global__ __launch_bounds__(256) void gv_k(const unsigned short* __restrict__ afH,
                                            const unsigned short* __restrict__ afL,
                                            float* __restrict__ gv) {
  int mol = blockIdx.x, c = threadIdx.x;
  float s = 0.f;
  for (int a = 0; a < 64; ++a) {
    size_t i = ((size_t)mol * 64 + a) * 256 + c;
    s += b2f(afH[i]) + b2f(afL[i]);
  }
  gv[mol * 256 + c] = s;
}

// graph head: relu(gv@G1+g1)@G2+g2 -> out[mol*12289+12288]
__global__ __launch_bounds__(512) void gh_k(const float* __restrict__ gv, const float* __restrict__ G1,
                                            const float* __restrict__ g1, const float* __restrict__ G2,
                                            const float* __restrict__ g2, float* __restrict__ out) {
  __shared__ float xs[256];
  __shared__ float red[512];
  int mol = blockIdx.x, j = threadIdx.x;
  if (j < 256) xs[j] = gv[mol * 256 + j];
  __syncthreads();
  float s = 0.f;
  for (int k = 0; k < 256; ++k) s += xs[k] * G1[k * 512 + j];
  s = fmaxf(s + g1[j], 0.f);
  red[j] = s * G2[j];
  __syncthreads();
  for (int st = 256; st > 0; st >>= 1) {
    if (j < st) red[j] += red[j + st];
    __syncthreads();
  }
  if (j == 0) out[(size_t)mol * OUT_STRIDE + 12288] = red[0] + g2[0];
}

extern "C" void kernel_launch(void* const* d_in, const int* in_sizes, int n_in,
                              void* d_out, int out_size, void* d_ws, size_t ws_size,
                              hipStream_t stream) {
  (void)in_sizes; (void)n_in; (void)out_size; (void)ws_size;
  const float* f_atoms  = (const float*)d_in[0];
  const float* f_bonds  = (const float*)d_in[1];
  const float* prev_hid = (const float*)d_in[2];
  const float* W_i   = (const float*)d_in[7];
  const float* W_h   = (const float*)d_in[8];
  const float* W_o   = (const float*)d_in[9];
  const float* b_o   = (const float*)d_in[10];
  const float* Wq    = (const float*)d_in[11];
  const float* Wk    = (const float*)d_in[12];
  const float* Wv    = (const float*)d_in[13];
  const float* Wattn = (const float*)d_in[14];
  const float* W_vv  = (const float*)d_in[15];
  const float* W_vc  = (const float*)d_in[16];
  const float* A1    = (const float*)d_in[17];
  const float* a1    = (const float*)d_in[18];
  const float* A2    = (const float*)d_in[19];
  const float* a2    = (const float*)d_in[20];
  const float* B1    = (const float*)d_in[21];
  const float* b1    = (const float*)d_in[22];
  const float* B2    = (const float*)d_in[23];
  const float* b2b   = (const float*)d_in[24];
  const float* G1    = (const float*)d_in[25];
  const float* g1    = (const float*)d_in[26];
  const float* G2    = (const float*)d_in[27];
  const float* g2    = (const float*)d_in[28];
  float* out = (float*)d_out;

  // ---- workspace (~172.8 MB < known-good 187.3) ----
  char* base = (char*)d_ws;
  float* h = (float*)(base);                                   // 134.2 MB fp32
  unsigned short* fbT = (unsigned short*)(base + 134217728);   // steps 0-2
  float* asumF = (float*)(base + 134217728);                   // step 3 on
  char* W0 = base + 167772160;                                 // weights ~5.1 MB
  unsigned short* WiTh   = (unsigned short*)(W0);
  unsigned short* WiTl   = (unsigned short*)(W0 + 65536);
  unsigned short* WhTh   = (unsigned short*)(W0 + 131072);
  unsigned short* WhTl   = (unsigned short*)(W0 + 262144);
  unsigned short* WoTh   = (unsigned short*)(W0 + 393216);
  unsigned short* WoTl   = (unsigned short*)(W0 + 589824);
  unsigned short* WqkvTh = (unsigned short*)(W0 + 786432);     // [768][256]
  unsigned short* WqkvTl = (unsigned short*)(W0 + 1179648);
  unsigned short* WaTh   = (unsigned short*)(W0 + 1572864);    // (unused, kept)
  unsigned short* WaTl   = (unsigned short*)(W0 + 1703936);
  unsigned short* Wcv2Th = (unsigned short*)(W0 + 1835008);    // [256][768]
  unsigned short* Wcv2Tl = (unsigned short*)(W0 + 2228224);
  unsigned short* A1Th   = (unsigned short*)(W0 + 2621440);
  unsigned short* A1Tl   = (unsigned short*)(W0 + 2883584);
  unsigned short* A2Th   = (unsigned short*)(W0 + 3145728);
  unsigned short* A2Tl   = (unsigned short*)(W0 + 3276800);
  unsigned short* B1bTh  = (unsigned short*)(W0 + 3407872);    // [1024][256]
  unsigned short* B1bTl  = (unsigned short*)(W0 + 3932160);
  unsigned short* B2Th   = (unsigned short*)(W0 + 4456448);
  unsigned short* B2Tl   = (unsigned short*)(W0 + 4489216);
  float* gvec            = (float*)(W0 + 4521984);
  // post-loop aliases (sequential-stream lifetimes audited):
  unsigned short* xAh  = (unsigned short*)(base);              // step 4-7
  unsigned short* xAl  = (unsigned short*)(base + 16777216);
  float* qkv           = (float*)(base + 33554432);            // step 5-6
  unsigned short* ctxh = (unsigned short*)(base + 134217728);  // step 6-7
  unsigned short* ctxl = (unsigned short*)(base + 150994944);
  unsigned short* atfh = (unsigned short*)(base + 67108864);   // fused 7+8 out
  unsigned short* atfl = (unsigned short*)(base + 83886080);
  unsigned short* t1h  = (unsigned short*)(base);              // step 9 (over xA)
  unsigned short* t1l  = (unsigned short*)(base + 33554432);
  unsigned short* Ph   = (unsigned short*)(base);              // step 10 unified P
  unsigned short* Pl   = (unsigned short*)(base + 100663296);

  // 0) all weight pre-converts + composed Wcv2 + B1b remap + f_bonds plane
  convAll<<<7840, 256, 0, stream>>>(
      W_i, W_h, W_o, Wq, Wk, Wv, Wattn, W_vc, W_vv, A1, A2, B1, B2,
      f_bonds, fbT,
      WiTh, WiTl, WhTh, WhTl, WoTh, WoTl, WqkvTh, WqkvTl, WaTh, WaTl,
      Wcv2Th, Wcv2Tl, A1Th, A1Tl, A2Th, A2Tl, B1bTh, B1bTl, B2Th, B2Tl);

  // 1) h = h0 = relu(fbT @ W_i)  (single-plane A, fp32 out)
  mgemm<6><<<dim3(1024, 2), 256, 0, stream>>>(
      fbT, nullptr, nullptr, nullptr, nullptr, WiTh, WiTl, 128,
      nullptr, nullptr, nullptr, nullptr,
      h, nullptr, N_DIR, 256, 128, 128, 256, 0, 1, 1);

  // 2) DMPNN loop: multi-launch msg_f4 (proven fastest structure)
  for (int d = 0; d < 9; ++d) {
    msg_f4<<<512, 1024, 73728, stream>>>(h, WhTh, WhTl, WiTh, WiTl, fbT);
  }

  // 3) a_in  (asumF overwrites fbT — fbT dead after the loop)
  asum_f<<<4096, 256, 0, stream>>>(h, asumF);
  // 4) a_feats = relu([asum | f_atoms] @ WoT + b_o)
  mgemm<2><<<dim3(256, 2), 256, 0, stream>>>(
      asumF, f_atoms, nullptr, nullptr, nullptr, WoTh, WoTl, 384,
      nullptr, nullptr, b_o, nullptr,
      xAh, xAl, N_ATOMS, 256, 354, 0, 256, 0, 1, 0);
  // 5) qkv fused (N=768, fp32 out)
  mgemm<1><<<dim3(256, 6), 256, 0, stream>>>(
      xAh, xAl, nullptr, nullptr, nullptr, WqkvTh, WqkvTl, 256,
      nullptr, nullptr, nullptr, nullptr,
      qkv, nullptr, N_ATOMS, 768, 256, 256, 768, 0, 0, 1);
  // 6) attention
  attn_k<<<4096, 64, 0, stream>>>(qkv, ctxh, ctxl);
  // 7+8) atom_feats = relu(ctx@Wac + xA@Wvc^T + prev@Wvv^T)  (K=768 fused)
  mgemm<7><<<dim3(256, 2), 256, 0, stream>>>(
      ctxh, ctxl, xAh, xAl, prev_hid, Wcv2Th, Wcv2Tl, 768,
      nullptr, nullptr, nullptr, nullptr,
      atfh, atfl, N_ATOMS, 256, 768, 256, 256, 0, 1, 0);
  // 9) atom head
  mgemm<1><<<dim3(256, 4), 256, 0, stream>>>(
      atfh, atfl, nullptr, nullptr, nullptr, A1Th, A1Tl, 256,
      nullptr, nullptr, a1, nullptr,
      t1h, t1l, N_ATOMS, 512, 256, 256, 512, 0, 1, 0);
  mgemm<1><<<dim3(256, 1), 256, 0, stream>>>(
      t1h, t1l, nullptr, nullptr, nullptr, A2Th, A2Tl, 512,
      nullptr, nullptr, a2, nullptr,
      out, nullptr, N_ATOMS, 128, 512, 512, 0, 0, 0, 2);
  // 10) bond head: unified P = atomf @ B1b (N=1024: [P1 | P2])
  mgemm<1><<<dim3(256, 8), 256, 0, stream>>>(
      atfh, atfl, nullptr, nullptr, nullptr, B1bTh, B1bTl, 256,
      nullptr, nullptr, nullptr, nullptr,
      Ph, Pl, N_ATOMS, 1024, 256, 256, 1024, 0, 0, 0);
  //     out_bond = relu(P[a0][k] + P[a1][512+k] + b1) @ B2 + b2b
  mgemm<5><<<dim3(512, 1), 256, 0, stream>>>(
      Ph, Pl, nullptr, nullptr, nullptr, B2Th, B2Tl, 512,
      nullptr, nullptr, b2b, b1,
      out, nullptr, N_UND, 32, 512, 0, 0, 0, 0, 3);
  // 11) graph head
  gv_k<<<512, 256, 0, stream>>>(atfh, atfl, gvec);
  gh_k<<<512, 512, 0, stream>>>(gvec, G1, g1, G2, g2, out);
}

// Round 13
// 1724.448 us; speedup vs baseline: 2.9473x; 1.0046x over previous
//
#include <hip/hip_runtime.h>
#include <cstdint>
#include <cstddef>

#define B_MOL 512
#define A_PER 64
#define ED_PER 256
#define N_ATOMS (B_MOL * A_PER)   // 32768
#define N_DIR (B_MOL * ED_PER)    // 131072
#define N_UND (B_MOL * 128)       // 65536
#define HID 256
#define OUT_STRIDE 12289
#define AP 40   // LDS pitch (shorts) for a 32-wide k row (mgemm)
#define CP 72   // combined-plane LDS pitch (shorts): 32 hi | 32 lo | 8 pad

typedef __attribute__((ext_vector_type(8))) short bf16x8;
typedef __attribute__((ext_vector_type(8))) unsigned short u16x8;
typedef __attribute__((ext_vector_type(4))) float f32x4;

#define MFMA(a, b, c) __builtin_amdgcn_mfma_f32_16x16x32_bf16(a, b, c, 0, 0, 0)

__device__ __forceinline__ float b2f(unsigned short s) {
  return __builtin_bit_cast(float, (unsigned)s << 16);
}
// split fp32 -> (hi, lo) bf16 planes: x ~= hi + lo, |err| <~ 2^-16 |x|
__device__ __forceinline__ void split2(float v, unsigned short& h, unsigned short& l) {
  unsigned ub = __builtin_bit_cast(unsigned, v);
  h = (unsigned short)(ub >> 16);
  float fh = __builtin_bit_cast(float, ub & 0xffff0000u);
  float r = v - fh;
  l = (unsigned short)(__builtin_bit_cast(unsigned, r) >> 16);
}
// fp32 -> bf16 round-to-nearest-even (for the fb single plane)
__device__ __forceinline__ unsigned short f2bf_rne(float v) {
  unsigned u = __builtin_bit_cast(unsigned, v);
  u += 0x7FFFu + ((u >> 16) & 1u);
  return (unsigned short)(u >> 16);
}
__device__ __forceinline__ int e_src(int e) {
  return (e < 64) ? e : (e < 128) ? (e - 64)
       : (e < 192) ? ((e - 127) & 63) : ((e - 190) & 63);
}

// ---------------------------------------------------------------------------
// convAll: ALL weight pre-converts in one launch. dst[n][k] split planes.
// Block map: [0,2048) 8 segs of 256 (Wi, Wh, Wo, Wq, Wk, Wv, Wattn, Wcv2);
// [2048,2560) A1; [2560,2688) A2; [2688,3712) B1b (N=1024 remap);
// [3712,3744) B2; [3744,7840) f_bonds -> bf16 RNE plane [131072][128].
// seg 7 (Wcv2, Kp=768): k<256 -> Wac[k][n]=dot(Wattn[k][:],Wvc[n][:]);
//   256..512 -> Wvc[n][k-256]; 512..768 -> Wvv[n][k-512].
// B1b [1024][256]: n<512 -> B1[k][n]; n>=512 -> B1[k+256][n-512].
// ---------------------------------------------------------------------------
__global__ __launch_bounds__(256) void convAll(
    const float* Wi, const float* Wh, const float* Wo,
    const float* Wq, const float* Wk, const float* Wv,
    const float* Wattn, const float* Wvc, const float* Wvv,
    const float* A1, const float* A2, const float* B1, const float* B2,
    const float* fbF, unsigned short* fbT,
    unsigned short* WiTh, unsigned short* WiTl,
    unsigned short* WhTh, unsigned short* WhTl,
    unsigned short* WoTh, unsigned short* WoTl,
    unsigned short* WqkvTh, unsigned short* WqkvTl,
    unsigned short* WaTh, unsigned short* WaTl,
    unsigned short* Wcv2Th, unsigned short* Wcv2Tl,
    unsigned short* A1Th, unsigned short* A1Tl,
    unsigned short* A2Th, unsigned short* A2Tl,
    unsigned short* B1bTh, unsigned short* B1bTl,
    unsigned short* B2Th, unsigned short* B2Tl) {
  int b = blockIdx.x;
  if (b >= 3744) {  // f_bonds convert: 32 edges per block, 8 thr/edge
    int e = (b - 3744) * 32 + (threadIdx.x >> 3);
    int ks = (threadIdx.x & 7) * 16;
    const float* s = fbF + (size_t)e * 111;
    u16x8 o0 = {0,0,0,0,0,0,0,0}, o1 = {0,0,0,0,0,0,0,0};
#pragma unroll
    for (int z = 0; z < 8; ++z) {
      int k = ks + z;
      if (k < 111) o0[z] = f2bf_rne(s[k]);
    }
#pragma unroll
    for (int z = 0; z < 8; ++z) {
      int k = ks + 8 + z;
      if (k < 111) o1[z] = f2bf_rne(s[k]);
    }
    *(u16x8*)&fbT[(size_t)e * 128 + ks] = o0;
    *(u16x8*)&fbT[(size_t)e * 128 + ks + 8] = o1;
    return;
  }
  if (b >= 1792 && b < 2048) {  // seg 7: Wcv2 combined [256][768]
    int n = b & 255;
    for (int k = threadIdx.x; k < 768; k += 256) {
      float v;
      if (k < 256) {
        v = 0.f;
        for (int j = 0; j < 256; ++j)
          v += Wattn[(size_t)k * 256 + j] * Wvc[(size_t)n * 256 + j];
      } else if (k < 512) {
        v = Wvc[(size_t)n * 256 + (k - 256)];
      } else {
        v = Wvv[(size_t)n * 256 + (k - 512)];
      }
      unsigned short h_, l_;
      split2(v, h_, l_);
      Wcv2Th[(size_t)n * 768 + k] = h_;
      Wcv2Tl[(size_t)n * 768 + k] = l_;
    }
    return;
  }
  if (b >= 2688 && b < 3712) {  // B1b remap [1024][256]
    int n = b - 2688;
    int k = threadIdx.x;  // 0..255
    float v = (n < 512) ? B1[(size_t)k * 512 + n]
                        : B1[(size_t)(k + 256) * 512 + (n - 512)];
    unsigned short h_, l_;
    split2(v, h_, l_);
    B1bTh[(size_t)n * 256 + k] = h_;
    B1bTl[(size_t)n * 256 + k] = l_;
    return;
  }
  const float* src = nullptr;
  unsigned short *dh = nullptr, *dl = nullptr;
  int K = 256, N = 256, Kp = 256, n = 0;
  if (b < 1792) {
    int seg = b >> 8; n = b & 255;
    switch (seg) {
      case 0: src = Wi; dh = WiTh; dl = WiTl; K = 111; Kp = 128; break;
      case 1: src = Wh; dh = WhTh; dl = WhTl; break;
      case 2: src = Wo; dh = WoTh; dl = WoTl; K = 354; Kp = 384; break;
      case 3: src = Wq; dh = WqkvTh; dl = WqkvTl; break;
      case 4: src = Wk; dh = WqkvTh + 65536; dl = WqkvTl + 65536; break;
      case 5: src = Wv; dh = WqkvTh + 131072; dl = WqkvTl + 131072; break;
      default: src = Wattn; dh = WaTh; dl = WaTl; break;  // seg 6 (kept)
    }
    for (int k = threadIdx.x; k < Kp; k += 256) {
      float v = 0.f;
      if (b >> 8 == 2) {
        if (k < 256) v = src[(size_t)(98 + k) * 256 + n];
        else if (k < 354) v = src[(size_t)(k - 256) * 256 + n];
      } else {
        if (k < K) v = src[(size_t)k * N + n];
      }
      unsigned short h_, l_;
      split2(v, h_, l_);
      dh[(size_t)n * Kp + k] = h_;
      dl[(size_t)n * Kp + k] = l_;
    }
    return;
  }
  if (b < 2560)      { n = b - 2048; src = A1; dh = A1Th; dl = A1Tl; K = 256; N = 512; Kp = 256; }
  else if (b < 2688) { n = b - 2560; src = A2; dh = A2Th; dl = A2Tl; K = 512; N = 128; Kp = 512; }
  else               { n = b - 3712; src = B2; dh = B2Th; dl = B2Tl; K = 512; N = 32;  Kp = 512; }
  for (int k = threadIdx.x; k < Kp; k += 256) {
    float v = (k < K) ? src[(size_t)k * N + n] : 0.f;
    unsigned short h_, l_;
    split2(v, h_, l_);
    dh[(size_t)n * Kp + k] = h_;
    dl[(size_t)n * Kp + k] = l_;
  }
}

// ---------------------------------------------------------------------------
// mgemm: split-bf16 MFMA GEMM. 128x128 tile, BK=32, 256 thr (4 waves, 2x2),
// 64x64/wave, 3 MFMA per frag-pair (2 for AMODE 6).
// B pre-split/pre-transposed global [N][Kp] planes (BTh/BTl, ldb=Kp).
// AMODE 0: fp32 A [M][lda]; 1: split A planes; 2: concat fp32 asumF|f_atoms;
//       5: bond combine relu(P[a0][k]+P[a1][512+k]+b), unified P (Aa/Ab);
//       6: SINGLE bf16 plane A (fb), 2 MFMA/frag;
//       7: triple concat: k<256 ctx(Aa/Ab), k<512 xA(Ac/Ad), k>=512 Af32;
//       8: FUSED a_sum: k<256 sum of 4 incoming h rows (Af32=h), else
//          f_atoms (Ab_) for k<354.
// outmode 0: split planes; 1: fp32 (+outcol); 2: atom-head; 3: bond-head.
// ---------------------------------------------------------------------------
template <int AMODE>
__launch_bounds__(256, 3)
__global__ void mgemm(const void* Aa_, const void* Ab_, const void* Ac_, const void* Ad_,
                      const float* __restrict__ Af32,
                      const unsigned short* __restrict__ BTh,
                      const unsigned short* __restrict__ BTl, int ldb,
                      const unsigned short* addH, const unsigned short* addL,
                      const float* __restrict__ bias,
                      const float* __restrict__ abias,
                      void* outA, void* outB,
                      int M, int N, int K, int lda, int ldco, int outcol,
                      int relu, int outmode) {
  __shared__ unsigned short AsH[128 * AP], AsL[128 * AP];
  __shared__ unsigned short BsH[128 * AP], BsL[128 * AP];
  const int tid = threadIdx.x;
  const int lane = tid & 63;
  const int l15 = lane & 15, l4 = lane >> 4;
  const int w = tid >> 6;
  const int wr = (w >> 1) * 64, wc = (w & 1) * 64;
  const int tileM = blockIdx.x * 128, tileN = blockIdx.y * 128;
  const int srow = tid >> 1;           // staging row 0..127
  const int sks = (tid & 1) * 16;      // staging k-seg {0,16}

  int rem = N - tileN - wc;
  int bnMax = rem >= 64 ? 4 : (rem > 0 ? (rem >> 4) : 0);

  f32x4 zf = {0.f, 0.f, 0.f, 0.f};
  f32x4 acc[4][4];
#pragma unroll
  for (int i = 0; i < 4; ++i)
#pragma unroll
    for (int j = 0; j < 4; ++j) acc[i][j] = zf;

  const int nkb = (K + 31) >> 5;
  for (int kb = 0; kb < nkb; ++kb) {
    __syncthreads();
    const int k0 = kb * 32 + sks;
    // ---- stage A ----
    {
      const int row = tileM + srow;
      if (AMODE == 6) {
        const unsigned short* Ah = (const unsigned short*)Aa_;
        size_t bse = (size_t)row * lda + k0;
        *(u16x8*)&AsH[srow * AP + sks]     = *(const u16x8*)&Ah[bse];
        *(u16x8*)&AsH[srow * AP + sks + 8] = *(const u16x8*)&Ah[bse + 8];
      } else if (AMODE == 1 || (AMODE == 7 && k0 < 512)) {
        const unsigned short* Ah; const unsigned short* Al;
        size_t bse;
        if (AMODE == 7) {
          Ah = (k0 < 256) ? (const unsigned short*)Aa_ : (const unsigned short*)Ac_;
          Al = (k0 < 256) ? (const unsigned short*)Ab_ : (const unsigned short*)Ad_;
          bse = (size_t)row * 256 + (k0 & 255);
        } else {
          Ah = (const unsigned short*)Aa_;
          Al = (const unsigned short*)Ab_;
          bse = (size_t)row * lda + k0;
        }
        *(u16x8*)&AsH[srow * AP + sks]     = *(const u16x8*)&Ah[bse];
        *(u16x8*)&AsH[srow * AP + sks + 8] = *(const u16x8*)&Ah[bse + 8];
        *(u16x8*)&AsL[srow * AP + sks]     = *(const u16x8*)&Al[bse];
        *(u16x8*)&AsL[srow * AP + sks + 8] = *(const u16x8*)&Al[bse + 8];
      } else if (AMODE == 5) {
        int mol = row >> 7, u = row & 127;
        int a0 = (u < 64) ? u : (u - 64);
        int a1v = (u < 64) ? ((u + 1) & 63) : ((u - 62) & 63);
        size_t p1 = (size_t)(mol * 64 + a0) * 1024 + k0;
        size_t p2 = (size_t)(mol * 64 + a1v) * 1024 + 512 + k0;
        const unsigned short* Ph = (const unsigned short*)Aa_;
        const unsigned short* Pl = (const unsigned short*)Ab_;
        u16x8 x1h[2] = {*(const u16x8*)&Ph[p1], *(const u16x8*)&Ph[p1 + 8]};
        u16x8 x1l[2] = {*(const u16x8*)&Pl[p1], *(const u16x8*)&Pl[p1 + 8]};
        u16x8 x2h[2] = {*(const u16x8*)&Ph[p2], *(const u16x8*)&Ph[p2 + 8]};
        u16x8 x2l[2] = {*(const u16x8*)&Pl[p2], *(const u16x8*)&Pl[p2 + 8]};
#pragma unroll
        for (int c = 0; c < 2; ++c) {
          u16x8 hv, lv;
#pragma unroll
          for (int z = 0; z < 8; ++z) {
            float v = b2f(x1h[c][z]) + b2f(x1l[c][z])
                    + b2f(x2h[c][z]) + b2f(x2l[c][z]) + abias[k0 + c * 8 + z];
            v = fmaxf(v, 0.f);
            unsigned short h_, l_;
            split2(v, h_, l_);
            hv[z] = h_; lv[z] = l_;
          }
          *(u16x8*)&AsH[srow * AP + sks + c * 8] = hv;
          *(u16x8*)&AsL[srow * AP + sks + c * 8] = lv;
        }
      } else if (AMODE == 8 && k0 < 256) {
        // fused a_sum: a_in[row][k] = sum of 4 incoming h rows (fp32, same
        // add order as the old asum_f kernel -> bitwise-identical)
        int mol = row >> 6, t = row & 63;
        const float* hb = Af32 + (size_t)mol * 65536;
        int ea0 = (t + 63) & 63;
        int ea1 = 64 + ((t + 62) & 63);
        int ea2 = 128 + t;
        int ea3 = 192 + t;
#pragma unroll
        for (int half = 0; half < 2; ++half) {
          int kk = k0 + half * 8;
          f32x4 s0, s1;
          {
            const float* p = hb + (size_t)ea0 * 256 + kk;
            s0 = *(const f32x4*)p;
            s1 = *(const f32x4*)(p + 4);
          }
          {
            const float* p = hb + (size_t)ea1 * 256 + kk;
            s0 += *(const f32x4*)p;
            s1 += *(const f32x4*)(p + 4);
          }
          {
            const float* p = hb + (size_t)ea2 * 256 + kk;
            s0 += *(const f32x4*)p;
            s1 += *(const f32x4*)(p + 4);
          }
          {
            const float* p = hb + (size_t)ea3 * 256 + kk;
            s0 += *(const f32x4*)p;
            s1 += *(const f32x4*)(p + 4);
          }
          u16x8 hv, lv;
#pragma unroll
          for (int z = 0; z < 4; ++z) {
            unsigned short h_, l_;
            split2(s0[z], h_, l_); hv[z] = h_; lv[z] = l_;
            split2(s1[z], h_, l_); hv[4 + z] = h_; lv[4 + z] = l_;
          }
          *(u16x8*)&AsH[srow * AP + sks + half * 8] = hv;
          *(u16x8*)&AsL[srow * AP + sks + half * 8] = lv;
        }
      } else {
        u16x8 hv0 = {0,0,0,0,0,0,0,0}, lv0 = {0,0,0,0,0,0,0,0};
        u16x8 hv1 = {0,0,0,0,0,0,0,0}, lv1 = {0,0,0,0,0,0,0,0};
#pragma unroll
        for (int z = 0; z < 16; ++z) {
          int k = k0 + z;
          float v = 0.f;
          if (AMODE == 0) {
            if (k < K) v = ((const float*)Aa_)[(size_t)row * lda + k];
          } else if (AMODE == 2) {
            if (k < 256) v = ((const float*)Aa_)[(size_t)row * 256 + k];
            else if (k < 354) v = ((const float*)Ab_)[(size_t)row * 98 + (k - 256)];
          } else if (AMODE == 8) {  // k0 >= 256 guaranteed here
            if (k < 354) v = ((const float*)Ab_)[(size_t)row * 98 + (k - 256)];
          } else {  // AMODE 7, k0 >= 512: prev_hid fp32
            v = Af32[(size_t)row * 256 + (k - 512)];
          }
          unsigned short h_, l_;
          split2(v, h_, l_);
          if (z < 8) { hv0[z] = h_; lv0[z] = l_; }
          else       { hv1[z - 8] = h_; lv1[z - 8] = l_; }
        }
        *(u16x8*)&AsH[srow * AP + sks]     = hv0;
        *(u16x8*)&AsH[srow * AP + sks + 8] = hv1;
        *(u16x8*)&AsL[srow * AP + sks]     = lv0;
        *(u16x8*)&AsL[srow * AP + sks + 8] = lv1;
      }
    }
    // ---- stage B ----
    {
      const int n = tileN + srow;
      if (n < N) {
        size_t bb = (size_t)n * ldb + k0;
        *(u16x8*)&BsH[srow * AP + sks]     = *(const u16x8*)&BTh[bb];
        *(u16x8*)&BsH[srow * AP + sks + 8] = *(const u16x8*)&BTh[bb + 8];
        *(u16x8*)&BsL[srow * AP + sks]     = *(const u16x8*)&BTl[bb];
        *(u16x8*)&BsL[srow * AP + sks + 8] = *(const u16x8*)&BTl[bb + 8];
      } else {
        u16x8 z8 = {0,0,0,0,0,0,0,0};
        *(u16x8*)&BsH[srow * AP + sks]     = z8;
        *(u16x8*)&BsH[srow * AP + sks + 8] = z8;
        *(u16x8*)&BsL[srow * AP + sks]     = z8;
        *(u16x8*)&BsL[srow * AP + sks + 8] = z8;
      }
    }
    __syncthreads();
    // ---- compute ----
    bf16x8 ah[4], al[4];
#pragma unroll
    for (int am = 0; am < 4; ++am) {
      int ar = wr + am * 16 + l15;
      ah[am] = *(const bf16x8*)&AsH[ar * AP + l4 * 8];
      if (AMODE != 6) al[am] = *(const bf16x8*)&AsL[ar * AP + l4 * 8];
    }
#pragma unroll
    for (int bn = 0; bn < 4; ++bn) {
      if (bn < bnMax) {
        int br = wc + bn * 16 + l15;
        bf16x8 bh = *(const bf16x8*)&BsH[br * AP + l4 * 8];
        bf16x8 bl = *(const bf16x8*)&BsL[br * AP + l4 * 8];
#pragma unroll
        for (int am = 0; am < 4; ++am) {
          acc[am][bn] = MFMA(ah[am], bh, acc[am][bn]);
          acc[am][bn] = MFMA(ah[am], bl, acc[am][bn]);
          if (AMODE != 6) acc[am][bn] = MFMA(al[am], bh, acc[am][bn]);
        }
      }
    }
  }

  // ---- epilogue ----
#pragma unroll
  for (int am = 0; am < 4; ++am) {
#pragma unroll
    for (int bn = 0; bn < 4; ++bn) {
      if (bn >= bnMax) continue;
      int col = tileN + wc + bn * 16 + l15;
      float bs = bias ? bias[col] : 0.f;
#pragma unroll
      for (int r = 0; r < 4; ++r) {
        size_t row = (size_t)tileM + wr + am * 16 + l4 * 4 + r;
        float v = acc[am][bn][r] + bs;
        if (addH) v += b2f(addH[row * 256 + col]) + b2f(addL[row * 256 + col]);
        if (relu) v = fmaxf(v, 0.f);
        if (outmode == 0) {
          unsigned short h_, l_;
          split2(v, h_, l_);
          ((unsigned short*)outA)[row * (size_t)ldco + col] = h_;
          ((unsigned short*)outB)[row * (size_t)ldco + col] = l_;
        } else if (outmode == 1) {
          ((float*)outA)[row * (size_t)ldco + outcol + col] = v;
        } else if (outmode == 2) {
          int mol = (int)(row >> 6), t = (int)(row & 63);
          ((float*)outA)[(size_t)mol * OUT_STRIDE + 4096 + t * 128 + col] = v;
        } else {
          int mol = (int)(row >> 7), u = (int)(row & 127);
          ((float*)outA)[(size_t)mol * OUT_STRIDE + u * 32 + col] = v;
        }
      }
    }
  }
}

// ---------------------------------------------------------------------------
// msg_f4: fused DMPNN iteration (proven), fp32 h, combined-plane LDS
// (73,728 B -> 2 blocks/CU). ONE BLOCK PER MOLECULE. 1024 thr = 16 waves
// (4M x 4N), wave tile 64x64, acc[4][4], BK=32. Multi-launch.
// ---------------------------------------------------------------------------
__launch_bounds__(1024)
__global__ void msg_f4(float* h,
                       const unsigned short* __restrict__ WhTh,
                       const unsigned short* __restrict__ WhTl,
                       const unsigned short* __restrict__ WiTh,
                       const unsigned short* __restrict__ WiTl,
                       const unsigned short* __restrict__ fbT) {
  extern __shared__ char smem_[];
  unsigned short* AsC = (unsigned short*)smem_;              // 256*72*2 = 36864 B
  unsigned short* BsC = (unsigned short*)(smem_ + 36864);    // 36864 B
  const int tid = threadIdx.x;
  const int lane = tid & 63, l15 = lane & 15, l4 = lane >> 4;
  const int w = tid >> 6;          // 0..15
  const int wm = (w >> 2) * 64;    // row base: 0,64,128,192
  const int wn = (w & 3) * 64;     // col base: 0,64,128,192
  const int mol = blockIdx.x;
  const int arow = tid >> 2;       // staging row 0..255 (edge id, identity)
  const int aks = (tid & 3) * 8;   // staging k sub-seg {0,8,16,24}

  f32x4 acc[4][4];
#pragma unroll
  for (int i = 0; i < 4; ++i)
#pragma unroll
    for (int j = 0; j < 4; ++j) acc[i][j] = (f32x4){0.f, 0.f, 0.f, 0.f};

  const int sA = e_src(arow);
  const int rvA = (arow < 128) ? (arow + 128) : (arow - 128);
  const int i0 = (sA + 63) & 63;
  const int i1 = 64 + ((sA + 62) & 63);
  const int i2 = 128 + sA;
  const int i3 = 192 + sA;
  const size_t hbase = (size_t)mol * 256 * 256;

  // ---- phase 1: acc = fbT @ Wi (K=128 padded -> 4 chunks of 32) ----
  const size_t fbb = (size_t)(mol * 256 + arow) * 128;
  for (int kb = 0; kb < 4; ++kb) {
    __syncthreads();
    {
      *(u16x8*)&AsC[arow * CP + aks] = *(const u16x8*)&fbT[fbb + kb * 32 + aks];
    }
    {
      size_t bb = (size_t)arow * 128 + kb * 32 + aks;  // Wi pitch 128
      *(u16x8*)&BsC[arow * CP + aks]      = *(const u16x8*)&WiTh[bb];
      *(u16x8*)&BsC[arow * CP + 32 + aks] = *(const u16x8*)&WiTl[bb];
    }
    __syncthreads();
    bf16x8 ah[4];
#pragma unroll
    for (int am = 0; am < 4; ++am) {
      int ar = wm + am * 16 + l15;
      ah[am] = *(const bf16x8*)&AsC[ar * CP + l4 * 8];
    }
#pragma unroll
    for (int bn = 0; bn < 4; ++bn) {
      int br = wn + bn * 16 + l15;
      bf16x8 bh = *(const bf16x8*)&BsC[br * CP + l4 * 8];
      bf16x8 bl = *(const bf16x8*)&BsC[br * CP + 32 + l4 * 8];
#pragma unroll
      for (int am = 0; am < 4; ++am) {
        acc[am][bn] = MFMA(ah[am], bh, acc[am][bn]);
        acc[am][bn] = MFMA(ah[am], bl, acc[am][bn]);
      }
    }
  }
  // mid-relu -> acc holds h0
#pragma unroll
  for (int i = 0; i < 4; ++i)
#pragma unroll
    for (int j = 0; j < 4; ++j)
#pragma unroll
      for (int r = 0; r < 4; ++r) acc[i][j][r] = fmaxf(acc[i][j][r], 0.f);

  // ---- phase 2: acc += m @ Wh, K=256 (8 chunks); fused a_sum staging ----
  for (int kb = 0; kb < 8; ++kb) {
    __syncthreads();
    {
      const int c0 = kb * 32 + aks;
      f32x4 m0, m1;
      {
        const float* p = &h[hbase + (size_t)i0 * 256 + c0];
        m0 = *(const f32x4*)p;
        m1 = *(const f32x4*)(p + 4);
      }
      {
        const float* p = &h[hbase + (size_t)i1 * 256 + c0];
        m0 += *(const f32x4*)p;
        m1 += *(const f32x4*)(p + 4);
      }
      {
        const float* p = &h[hbase + (size_t)i2 * 256 + c0];
        m0 += *(const f32x4*)p;
        m1 += *(const f32x4*)(p + 4);
      }
      {
        const float* p = &h[hbase + (size_t)i3 * 256 + c0];
        m0 += *(const f32x4*)p;
        m1 += *(const f32x4*)(p + 4);
      }
      {
        const float* p = &h[hbase + (size_t)rvA * 256 + c0];
        m0 -= *(const f32x4*)p;
        m1 -= *(const f32x4*)(p + 4);
      }
      u16x8 hv, lv;
#pragma unroll
      for (int z = 0; z < 4; ++z) {
        unsigned short h_, l_;
        split2(m0[z], h_, l_); hv[z] = h_; lv[z] = l_;
        split2(m1[z], h_, l_); hv[4 + z] = h_; lv[4 + z] = l_;
      }
      *(u16x8*)&AsC[arow * CP + aks]      = hv;
      *(u16x8*)&AsC[arow * CP + 32 + aks] = lv;
    }
    {
      size_t bb = (size_t)arow * 256 + kb * 32 + aks;  // Wh pitch 256
      *(u16x8*)&BsC[arow * CP + aks]      = *(const u16x8*)&WhTh[bb];
      *(u16x8*)&BsC[arow * CP + 32 + aks] = *(const u16x8*)&WhTl[bb];
    }
    __syncthreads();
    bf16x8 ah[4], al[4];
#pragma unroll
    for (int am = 0; am < 4; ++am) {
      int ar = wm + am * 16 + l15;
      ah[am] = *(const bf16x8*)&AsC[ar * CP + l4 * 8];
      al[am] = *(const bf16x8*)&AsC[ar * CP + 32 + l4 * 8];
    }
#pragma unroll
    for (int bn = 0; bn < 4; ++bn) {
      int br = wn + bn * 16 + l15;
      bf16x8 bh = *(const bf16x8*)&BsC[br * CP + l4 * 8];
      bf16x8 bl = *(const bf16x8*)&BsC[br * CP + 32 + l4 * 8];
#pragma unroll
      for (int am = 0; am < 4; ++am) {
        acc[am][bn] = MFMA(ah[am], bh, acc[am][bn]);
        acc[am][bn] = MFMA(ah[am], bl, acc[am][bn]);
        acc[am][bn] = MFMA(al[am], bh, acc[am][bn]);
      }
    }
  }

  // ---- epilogue: h = relu(acc) fp32, in-place (block owns its rows) ----
#pragma unroll
  for (int am = 0; am < 4; ++am) {
#pragma unroll
    for (int r = 0; r < 4; ++r) {
      int row = wm + am * 16 + l4 * 4 + r;
      size_t rowb = hbase + (size_t)row * 256;
#pragma unroll
      for (int bn = 0; bn < 4; ++bn) {
        int col = wn + bn * 16 + l15;
        h[rowb + col] = fmaxf(acc[am][bn][r], 0.f);
      }
    }
  }
}

// flash attention, fp32 qkv in, split ctx out: one wave per (mol, head)
__global__ __launch_bounds__(64) void attn_k(const float* __restrict__ qkv,
                                             unsigned short* __restrict__ ctxH,
                                             unsigned short* __restrict__ ctxL) {
  __shared__ float kls[64 * 32];
  __shared__ float vls[64 * 32];
  int mol = blockIdx.x >> 3, head = blockIdx.x & 7;
  int lane = threadIdx.x;
  size_t rb = ((size_t)(mol * 64 + lane)) * 768 + head * 32;
#pragma unroll
  for (int c = 0; c < 8; ++c) {
    *(float4*)(kls + lane * 32 + c * 4) = *(const float4*)(qkv + rb + 256 + c * 4);
    *(float4*)(vls + lane * 32 + c * 4) = *(const float4*)(qkv + rb + 512 + c * 4);
  }
  float q[32];
#pragma unroll
  for (int d = 0; d < 32; ++d) q[d] = qkv[rb + d];
  __syncthreads();
  float mx = -1e30f, l = 0.f;
  float acc[32];
#pragma unroll
  for (int d = 0; d < 32; ++d) acc[d] = 0.f;
  for (int j = 0; j < 64; ++j) {
    float s = 0.f;
#pragma unroll
    for (int d = 0; d < 32; ++d) s += q[d] * kls[j * 32 + d];
    s *= 0.17677669529663687f;  // 1/sqrt(32)
    float nm = fmaxf(mx, s);
    float co = __expf(mx - nm);
    float p = __expf(s - nm);
    l = l * co + p;
#pragma unroll
    for (int d = 0; d < 32; ++d) acc[d] = acc[d] * co + p * vls[j * 32 + d];
    mx = nm;
  }
  float inv = 1.f / l;
  size_t ob = ((size_t)(mol * 64 + lane)) * 256 + head * 32;
#pragma unroll
  for (int d = 0; d < 32; ++d) {
    unsigned short h_, l_;
    split2(acc[d] * inv, h_, l_);
    ctxH[ob + d] = h_;
    ctxL[ob + d] = l_;
  }
}

// merged graph head: gv in-block, then relu(gv@G1+g1)@G2+g2
__global__ __launch_bounds__(512) void gvh_k(const unsigned short* __restrict__ afH,
                                             const unsigned short* __restrict__ afL,
                                             const float* __restrict__ G1,
                                             const float* __restrict__ g1,
                                             const float* __restrict__ G2,
                                             const float* __restrict__ g2,
                                             float* __restrict__ out) {
  __shared__ float xs[256];
  __shared__ float red[512];
  int mol = blockIdx.x, j = threadIdx.x;
  if (j < 256) {
    float s = 0.f;
    for (int a = 0; a < 64; ++a) {
      size_t i = ((size_t)mol * 64 + a) * 256 + j;
      s += b2f(afH[i]) + b2f(afL[i]);
    }
    xs[j] = s;
  }
  __syncthreads();
  float s = 0.f;
  for (int k = 0; k < 256; ++k) s += xs[k] * G1[k * 512 + j];
  s = fmaxf(s + g1[j], 0.f);
  red[j] = s * G2[j];
  __syncthreads();
  for (int st = 256; st > 0; st >>= 1) {
    if (j < st) red[j] += red[j + st];
    __syncthreads();
  }
  if (j == 0) out[(size_t)mol * OUT_STRIDE + 12288] = red[0] + g2[0];
}

extern "C" void kernel_launch(void* const* d_in, const int* in_sizes, int n_in,
                              void* d_out, int out_size, void* d_ws, size_t ws_size,
                              hipStream_t stream) {
  (void)in_sizes; (void)n_in; (void)out_size; (void)ws_size;
  const float* f_atoms  = (const float*)d_in[0];
  const float* f_bonds  = (const float*)d_in[1];
  const float* prev_hid = (const float*)d_in[2];
  const float* W_i   = (const float*)d_in[7];
  const float* W_h   = (const float*)d_in[8];
  const float* W_o   = (const float*)d_in[9];
  const float* b_o   = (const float*)d_in[10];
  const float* Wq    = (const float*)d_in[11];
  const float* Wk    = (const float*)d_in[12];
  const float* Wv    = (const float*)d_in[13];
  const float* Wattn = (const float*)d_in[14];
  const float* W_vv  = (const float*)d_in[15];
  const float* W_vc  = (const float*)d_in[16];
  const float* A1    = (const float*)d_in[17];
  const float* a1    = (const float*)d_in[18];
  const float* A2    = (const float*)d_in[19];
  const float* a2    = (const float*)d_in[20];
  const float* B1    = (const float*)d_in[21];
  const float* b1    = (const float*)d_in[22];
  const float* B2    = (const float*)d_in[23];
  const float* b2b   = (const float*)d_in[24];
  const float* G1    = (const float*)d_in[25];
  const float* g1    = (const float*)d_in[26];
  const float* G2    = (const float*)d_in[27];
  const float* g2    = (const float*)d_in[28];
  float* out = (float*)d_out;

  // ---- workspace (~172.8 MB < known-good 187.3) ----
  char* base = (char*)d_ws;
  float* h = (float*)(base);                                   // 134.2 MB fp32
  unsigned short* fbT = (unsigned short*)(base + 134217728);   // steps 0-2 (32 MB)
  char* W0 = base + 167772160;                                 // weights ~5.1 MB
  unsigned short* WiTh   = (unsigned short*)(W0);
  unsigned short* WiTl   = (unsigned short*)(W0 + 65536);
  unsigned short* WhTh   = (unsigned short*)(W0 + 131072);
  unsigned short* WhTl   = (unsigned short*)(W0 + 262144);
  unsigned short* WoTh   = (unsigned short*)(W0 + 393216);
  unsigned short* WoTl   = (unsigned short*)(W0 + 589824);
  unsigned short* WqkvTh = (unsigned short*)(W0 + 786432);     // [768][256]
  unsigned short* WqkvTl = (unsigned short*)(W0 + 1179648);
  unsigned short* WaTh   = (unsigned short*)(W0 + 1572864);    // (unused, kept)
  unsigned short* WaTl   = (unsigned short*)(W0 + 1703936);
  unsigned short* Wcv2Th = (unsigned short*)(W0 + 1835008);    // [256][768]
  unsigned short* Wcv2Tl = (unsigned short*)(W0 + 2228224);
  unsigned short* A1Th   = (unsigned short*)(W0 + 2621440);
  unsigned short* A1Tl   = (unsigned short*)(W0 + 2883584);
  unsigned short* A2Th   = (unsigned short*)(W0 + 3145728);
  unsigned short* A2Tl   = (unsigned short*)(W0 + 3276800);
  unsigned short* B1bTh  = (unsigned short*)(W0 + 3407872);    // [1024][256]
  unsigned short* B1bTl  = (unsigned short*)(W0 + 3932160);
  unsigned short* B2Th   = (unsigned short*)(W0 + 4456448);
  unsigned short* B2Tl   = (unsigned short*)(W0 + 4489216);
  // post-loop aliases (lifetimes re-audited for the asum-fusion relayout):
  //   step 4: reads h [0,134.2M), writes xA at [134.2M,167.8M) (over dead fbT)
  //   step 5: reads xA, writes qkv [33.5M,134.2M) (h dead)
  //   step 6: reads qkv, writes ctx [0,33.5M)
  //   step 7+8: reads ctx+xA+prev_hid, writes atf [67.1M,100.7M) (over qkv)
  //   step 9: reads atf, writes t1 [0,67.1M) (ctx+qkv dead); A2 reads t1
  //   step 10: reads atf, writes P hi [0,67.1M) (t1 dead), lo [100.7M,167.8M)
  unsigned short* xAh  = (unsigned short*)(base + 134217728);
  unsigned short* xAl  = (unsigned short*)(base + 150994944);
  float* qkv           = (float*)(base + 33554432);
  unsigned short* ctxh = (unsigned short*)(base);
  unsigned short* ctxl = (unsigned short*)(base + 16777216);
  unsigned short* atfh = (unsigned short*)(base + 67108864);
  unsigned short* atfl = (unsigned short*)(base + 83886080);
  unsigned short* t1h  = (unsigned short*)(base);
  unsigned short* t1l  = (unsigned short*)(base + 33554432);
  unsigned short* Ph   = (unsigned short*)(base);
  unsigned short* Pl   = (unsigned short*)(base + 100663296);

  // 0) all weight pre-converts + composed Wcv2 + B1b remap + f_bonds plane
  convAll<<<7840, 256, 0, stream>>>(
      W_i, W_h, W_o, Wq, Wk, Wv, Wattn, W_vc, W_vv, A1, A2, B1, B2,
      f_bonds, fbT,
      WiTh, WiTl, WhTh, WhTl, WoTh, WoTl, WqkvTh, WqkvTl, WaTh, WaTl,
      Wcv2Th, Wcv2Tl, A1Th, A1Tl, A2Th, A2Tl, B1bTh, B1bTl, B2Th, B2Tl);

  // 1) h = h0 = relu(fbT @ W_i)  (single-plane A, fp32 out)
  mgemm<6><<<dim3(1024, 2), 256, 0, stream>>>(
      fbT, nullptr, nullptr, nullptr, nullptr, WiTh, WiTl, 128,
      nullptr, nullptr, nullptr, nullptr,
      h, nullptr, N_DIR, 256, 128, 128, 256, 0, 1, 1);

  // 2) DMPNN loop: multi-launch msg_f4 (proven fastest structure)
  for (int d = 0; d < 9; ++d) {
    msg_f4<<<512, 1024, 73728, stream>>>(h, WhTh, WhTl, WiTh, WiTl, fbT);
  }

  // 3+4) a_feats = relu([a_sum(h) | f_atoms] @ WoT + b_o)  (a_sum fused into
  //      the A-staging; xA written over dead fbT region)
  mgemm<8><<<dim3(256, 2), 256, 0, stream>>>(
      nullptr, f_atoms, nullptr, nullptr, h, WoTh, WoTl, 384,
      nullptr, nullptr, b_o, nullptr,
      xAh, xAl, N_ATOMS, 256, 354, 0, 256, 0, 1, 0);
  // 5) qkv fused (N=768, fp32 out)
  mgemm<1><<<dim3(256, 6), 256, 0, stream>>>(
      xAh, xAl, nullptr, nullptr, nullptr, WqkvTh, WqkvTl, 256,
      nullptr, nullptr, nullptr, nullptr,
      qkv, nullptr, N_ATOMS, 768, 256, 256, 768, 0, 0, 1);
  // 6) attention
  attn_k<<<4096, 64, 0, stream>>>(qkv, ctxh, ctxl);
  // 7+8) atom_feats = relu(ctx@Wac + xA@Wvc^T + prev@Wvv^T)  (K=768 fused)
  mgemm<7><<<dim3(256, 2), 256, 0, stream>>>(
      ctxh, ctxl, xAh, xAl, prev_hid, Wcv2Th, Wcv2Tl, 768,
      nullptr, nullptr, nullptr, nullptr,
      atfh, atfl, N_ATOMS, 256, 768, 256, 256, 0, 1, 0);
  // 9) atom head
  mgemm<1><<<dim3(256, 4), 256, 0, stream>>>(
      atfh, atfl, nullptr, nullptr, nullptr, A1Th, A1Tl, 256,
      nullptr, nullptr, a1, nullptr,
      t1h, t1l, N_ATOMS, 512, 256, 256, 512, 0, 1, 0);
  mgemm<1><<<dim3(256, 1), 256, 0, stream>>>(
      t1h, t1l, nullptr, nullptr, nullptr, A2Th, A2Tl, 512,
      nullptr, nullptr, a2, nullptr,
      out, nullptr, N_ATOMS, 128, 512, 512, 0, 0, 0, 2);
  // 10) bond head: unified P = atomf @ B1b (N=1024: [P1 | P2])
  mgemm<1><<<dim3(256, 8), 256, 0, stream>>>(
      atfh, atfl, nullptr, nullptr, nullptr, B1bTh, B1bTl, 256,
      nullptr, nullptr, nullptr, nullptr,
      Ph, Pl, N_ATOMS, 1024, 256, 256, 1024, 0, 0, 0);
  //     out_bond = relu(P[a0][k] + P[a1][512+k] + b1) @ B2 + b2b
  mgemm<5><<<dim3(512, 1), 256, 0, stream>>>(
      Ph, Pl, nullptr, nullptr, nullptr, B2Th, B2Tl, 512,
      nullptr, nullptr, b2b, b1,
      out, nullptr, N_UND, 32, 512, 0, 0, 0, 0, 3);
  // 11) graph head (gv + MLP merged)
  gvh_k<<<512, 512, 0, stream>>>(atfh, atfl, G1, g1, G2, g2, out);
}

// Round 14
// 1617.016 us; speedup vs baseline: 3.1431x; 1.0664x over previous
//
#include <hip/hip_runtime.h>
#include <cstdint>
#include <cstddef>

#define B_MOL 512
#define A_PER 64
#define ED_PER 256
#define N_ATOMS (B_MOL * A_PER)   // 32768
#define N_DIR (B_MOL * ED_PER)    // 131072
#define N_UND (B_MOL * 128)       // 65536
#define HID 256
#define OUT_STRIDE 12289
#define AP 40   // LDS pitch (shorts) for a 32-wide k row (mgemm)
#define CP 72   // combined-plane LDS pitch (shorts): 32 hi | 32 lo | 8 pad
#define BUFB 73728  // one msg_f6 LDS buffer: A (36864) + B (36864)

typedef __attribute__((ext_vector_type(8))) short bf16x8;
typedef __attribute__((ext_vector_type(8))) unsigned short u16x8;
typedef __attribute__((ext_vector_type(4))) float f32x4;

#define MFMA(a, b, c) __builtin_amdgcn_mfma_f32_16x16x32_bf16(a, b, c, 0, 0, 0)

__device__ __forceinline__ float b2f(unsigned short s) {
  return __builtin_bit_cast(float, (unsigned)s << 16);
}
// split fp32 -> (hi, lo) bf16 planes: x ~= hi + lo, |err| <~ 2^-16 |x|
__device__ __forceinline__ void split2(float v, unsigned short& h, unsigned short& l) {
  unsigned ub = __builtin_bit_cast(unsigned, v);
  h = (unsigned short)(ub >> 16);
  float fh = __builtin_bit_cast(float, ub & 0xffff0000u);
  float r = v - fh;
  l = (unsigned short)(__builtin_bit_cast(unsigned, r) >> 16);
}
// fp32 -> bf16 round-to-nearest-even (for the fb single plane)
__device__ __forceinline__ unsigned short f2bf_rne(float v) {
  unsigned u = __builtin_bit_cast(unsigned, v);
  u += 0x7FFFu + ((u >> 16) & 1u);
  return (unsigned short)(u >> 16);
}
__device__ __forceinline__ int e_src(int e) {
  return (e < 64) ? e : (e < 128) ? (e - 64)
       : (e < 192) ? ((e - 127) & 63) : ((e - 190) & 63);
}

// ---------------------------------------------------------------------------
// convAll: ALL weight pre-converts in one launch. dst[n][k] split planes.
// Block map: [0,2048) 8 segs of 256 (Wi, Wh, Wo, Wq, Wk, Wv, Wattn, Wcv2);
// [2048,2560) A1; [2560,2688) A2; [2688,3712) B1b (N=1024 remap);
// [3712,3744) B2; [3744,7840) f_bonds -> bf16 RNE plane [131072][128].
// ---------------------------------------------------------------------------
__global__ __launch_bounds__(256) void convAll(
    const float* Wi, const float* Wh, const float* Wo,
    const float* Wq, const float* Wk, const float* Wv,
    const float* Wattn, const float* Wvc, const float* Wvv,
    const float* A1, const float* A2, const float* B1, const float* B2,
    const float* fbF, unsigned short* fbT,
    unsigned short* WiTh, unsigned short* WiTl,
    unsigned short* WhTh, unsigned short* WhTl,
    unsigned short* WoTh, unsigned short* WoTl,
    unsigned short* WqkvTh, unsigned short* WqkvTl,
    unsigned short* WaTh, unsigned short* WaTl,
    unsigned short* Wcv2Th, unsigned short* Wcv2Tl,
    unsigned short* A1Th, unsigned short* A1Tl,
    unsigned short* A2Th, unsigned short* A2Tl,
    unsigned short* B1bTh, unsigned short* B1bTl,
    unsigned short* B2Th, unsigned short* B2Tl) {
  int b = blockIdx.x;
  if (b >= 3744) {  // f_bonds convert: 32 edges per block, 8 thr/edge
    int e = (b - 3744) * 32 + (threadIdx.x >> 3);
    int ks = (threadIdx.x & 7) * 16;
    const float* s = fbF + (size_t)e * 111;
    u16x8 o0 = {0,0,0,0,0,0,0,0}, o1 = {0,0,0,0,0,0,0,0};
#pragma unroll
    for (int z = 0; z < 8; ++z) {
      int k = ks + z;
      if (k < 111) o0[z] = f2bf_rne(s[k]);
    }
#pragma unroll
    for (int z = 0; z < 8; ++z) {
      int k = ks + 8 + z;
      if (k < 111) o1[z] = f2bf_rne(s[k]);
    }
    *(u16x8*)&fbT[(size_t)e * 128 + ks] = o0;
    *(u16x8*)&fbT[(size_t)e * 128 + ks + 8] = o1;
    return;
  }
  if (b >= 1792 && b < 2048) {  // seg 7: Wcv2 combined [256][768]
    int n = b & 255;
    for (int k = threadIdx.x; k < 768; k += 256) {
      float v;
      if (k < 256) {
        v = 0.f;
        for (int j = 0; j < 256; ++j)
          v += Wattn[(size_t)k * 256 + j] * Wvc[(size_t)n * 256 + j];
      } else if (k < 512) {
        v = Wvc[(size_t)n * 256 + (k - 256)];
      } else {
        v = Wvv[(size_t)n * 256 + (k - 512)];
      }
      unsigned short h_, l_;
      split2(v, h_, l_);
      Wcv2Th[(size_t)n * 768 + k] = h_;
      Wcv2Tl[(size_t)n * 768 + k] = l_;
    }
    return;
  }
  if (b >= 2688 && b < 3712) {  // B1b remap [1024][256]
    int n = b - 2688;
    int k = threadIdx.x;  // 0..255
    float v = (n < 512) ? B1[(size_t)k * 512 + n]
                        : B1[(size_t)(k + 256) * 512 + (n - 512)];
    unsigned short h_, l_;
    split2(v, h_, l_);
    B1bTh[(size_t)n * 256 + k] = h_;
    B1bTl[(size_t)n * 256 + k] = l_;
    return;
  }
  const float* src = nullptr;
  unsigned short *dh = nullptr, *dl = nullptr;
  int K = 256, N = 256, Kp = 256, n = 0;
  if (b < 1792) {
    int seg = b >> 8; n = b & 255;
    switch (seg) {
      case 0: src = Wi; dh = WiTh; dl = WiTl; K = 111; Kp = 128; break;
      case 1: src = Wh; dh = WhTh; dl = WhTl; break;
      case 2: src = Wo; dh = WoTh; dl = WoTl; K = 354; Kp = 384; break;
      case 3: src = Wq; dh = WqkvTh; dl = WqkvTl; break;
      case 4: src = Wk; dh = WqkvTh + 65536; dl = WqkvTl + 65536; break;
      case 5: src = Wv; dh = WqkvTh + 131072; dl = WqkvTl + 131072; break;
      default: src = Wattn; dh = WaTh; dl = WaTl; break;  // seg 6 (kept)
    }
    for (int k = threadIdx.x; k < Kp; k += 256) {
      float v = 0.f;
      if (b >> 8 == 2) {
        if (k < 256) v = src[(size_t)(98 + k) * 256 + n];
        else if (k < 354) v = src[(size_t)(k - 256) * 256 + n];
      } else {
        if (k < K) v = src[(size_t)k * N + n];
      }
      unsigned short h_, l_;
      split2(v, h_, l_);
      dh[(size_t)n * Kp + k] = h_;
      dl[(size_t)n * Kp + k] = l_;
    }
    return;
  }
  if (b < 2560)      { n = b - 2048; src = A1; dh = A1Th; dl = A1Tl; K = 256; N = 512; Kp = 256; }
  else if (b < 2688) { n = b - 2560; src = A2; dh = A2Th; dl = A2Tl; K = 512; N = 128; Kp = 512; }
  else               { n = b - 3712; src = B2; dh = B2Th; dl = B2Tl; K = 512; N = 32;  Kp = 512; }
  for (int k = threadIdx.x; k < Kp; k += 256) {
    float v = (k < K) ? src[(size_t)k * N + n] : 0.f;
    unsigned short h_, l_;
    split2(v, h_, l_);
    dh[(size_t)n * Kp + k] = h_;
    dl[(size_t)n * Kp + k] = l_;
  }
}

// ---------------------------------------------------------------------------
// mgemm: split-bf16 MFMA GEMM. 128x128 tile, BK=32, 256 thr (4 waves, 2x2),
// 64x64/wave, 3 MFMA per frag-pair (2 for AMODE 6).
// AMODE 0: fp32 A [M][lda]; 1: split A planes; 2: concat fp32 asumF|f_atoms;
//       5: bond combine relu(P[a0][k]+P[a1][512+k]+b), unified P (Aa/Ab);
//       6: SINGLE bf16 plane A (fb), 2 MFMA/frag;
//       7: triple concat: k<256 ctx(Aa/Ab), k<512 xA(Ac/Ad), k>=512 Af32;
//       8: FUSED a_sum: k<256 sum of 4 incoming h rows (Af32=h), else
//          f_atoms (Ab_) for k<354.
// outmode 0: split planes; 1: fp32 (+outcol); 2: atom-head; 3: bond-head.
// ---------------------------------------------------------------------------
template <int AMODE>
__launch_bounds__(256, 3)
__global__ void mgemm(const void* Aa_, const void* Ab_, const void* Ac_, const void* Ad_,
                      const float* __restrict__ Af32,
                      const unsigned short* __restrict__ BTh,
                      const unsigned short* __restrict__ BTl, int ldb,
                      const unsigned short* addH, const unsigned short* addL,
                      const float* __restrict__ bias,
                      const float* __restrict__ abias,
                      void* outA, void* outB,
                      int M, int N, int K, int lda, int ldco, int outcol,
                      int relu, int outmode) {
  __shared__ unsigned short AsH[128 * AP], AsL[128 * AP];
  __shared__ unsigned short BsH[128 * AP], BsL[128 * AP];
  const int tid = threadIdx.x;
  const int lane = tid & 63;
  const int l15 = lane & 15, l4 = lane >> 4;
  const int w = tid >> 6;
  const int wr = (w >> 1) * 64, wc = (w & 1) * 64;
  const int tileM = blockIdx.x * 128, tileN = blockIdx.y * 128;
  const int srow = tid >> 1;           // staging row 0..127
  const int sks = (tid & 1) * 16;      // staging k-seg {0,16}

  int rem = N - tileN - wc;
  int bnMax = rem >= 64 ? 4 : (rem > 0 ? (rem >> 4) : 0);

  f32x4 zf = {0.f, 0.f, 0.f, 0.f};
  f32x4 acc[4][4];
#pragma unroll
  for (int i = 0; i < 4; ++i)
#pragma unroll
    for (int j = 0; j < 4; ++j) acc[i][j] = zf;

  const int nkb = (K + 31) >> 5;
  for (int kb = 0; kb < nkb; ++kb) {
    __syncthreads();
    const int k0 = kb * 32 + sks;
    // ---- stage A ----
    {
      const int row = tileM + srow;
      if (AMODE == 6) {
        const unsigned short* Ah = (const unsigned short*)Aa_;
        size_t bse = (size_t)row * lda + k0;
        *(u16x8*)&AsH[srow * AP + sks]     = *(const u16x8*)&Ah[bse];
        *(u16x8*)&AsH[srow * AP + sks + 8] = *(const u16x8*)&Ah[bse + 8];
      } else if (AMODE == 1 || (AMODE == 7 && k0 < 512)) {
        const unsigned short* Ah; const unsigned short* Al;
        size_t bse;
        if (AMODE == 7) {
          Ah = (k0 < 256) ? (const unsigned short*)Aa_ : (const unsigned short*)Ac_;
          Al = (k0 < 256) ? (const unsigned short*)Ab_ : (const unsigned short*)Ad_;
          bse = (size_t)row * 256 + (k0 & 255);
        } else {
          Ah = (const unsigned short*)Aa_;
          Al = (const unsigned short*)Ab_;
          bse = (size_t)row * lda + k0;
        }
        *(u16x8*)&AsH[srow * AP + sks]     = *(const u16x8*)&Ah[bse];
        *(u16x8*)&AsH[srow * AP + sks + 8] = *(const u16x8*)&Ah[bse + 8];
        *(u16x8*)&AsL[srow * AP + sks]     = *(const u16x8*)&Al[bse];
        *(u16x8*)&AsL[srow * AP + sks + 8] = *(const u16x8*)&Al[bse + 8];
      } else if (AMODE == 5) {
        int mol = row >> 7, u = row & 127;
        int a0 = (u < 64) ? u : (u - 64);
        int a1v = (u < 64) ? ((u + 1) & 63) : ((u - 62) & 63);
        size_t p1 = (size_t)(mol * 64 + a0) * 1024 + k0;
        size_t p2 = (size_t)(mol * 64 + a1v) * 1024 + 512 + k0;
        const unsigned short* Ph = (const unsigned short*)Aa_;
        const unsigned short* Pl = (const unsigned short*)Ab_;
        u16x8 x1h[2] = {*(const u16x8*)&Ph[p1], *(const u16x8*)&Ph[p1 + 8]};
        u16x8 x1l[2] = {*(const u16x8*)&Pl[p1], *(const u16x8*)&Pl[p1 + 8]};
        u16x8 x2h[2] = {*(const u16x8*)&Ph[p2], *(const u16x8*)&Ph[p2 + 8]};
        u16x8 x2l[2] = {*(const u16x8*)&Pl[p2], *(const u16x8*)&Pl[p2 + 8]};
#pragma unroll
        for (int c = 0; c < 2; ++c) {
          u16x8 hv, lv;
#pragma unroll
          for (int z = 0; z < 8; ++z) {
            float v = b2f(x1h[c][z]) + b2f(x1l[c][z])
                    + b2f(x2h[c][z]) + b2f(x2l[c][z]) + abias[k0 + c * 8 + z];
            v = fmaxf(v, 0.f);
            unsigned short h_, l_;
            split2(v, h_, l_);
            hv[z] = h_; lv[z] = l_;
          }
          *(u16x8*)&AsH[srow * AP + sks + c * 8] = hv;
          *(u16x8*)&AsL[srow * AP + sks + c * 8] = lv;
        }
      } else if (AMODE == 8 && k0 < 256) {
        // fused a_sum: a_in[row][k] = sum of 4 incoming h rows (fp32, same
        // add order as the old asum_f kernel -> bitwise-identical)
        int mol = row >> 6, t = row & 63;
        const float* hb = Af32 + (size_t)mol * 65536;
        int ea0 = (t + 63) & 63;
        int ea1 = 64 + ((t + 62) & 63);
        int ea2 = 128 + t;
        int ea3 = 192 + t;
#pragma unroll
        for (int half = 0; half < 2; ++half) {
          int kk = k0 + half * 8;
          f32x4 s0, s1;
          {
            const float* p = hb + (size_t)ea0 * 256 + kk;
            s0 = *(const f32x4*)p;
            s1 = *(const f32x4*)(p + 4);
          }
          {
            const float* p = hb + (size_t)ea1 * 256 + kk;
            s0 += *(const f32x4*)p;
            s1 += *(const f32x4*)(p + 4);
          }
          {
            const float* p = hb + (size_t)ea2 * 256 + kk;
            s0 += *(const f32x4*)p;
            s1 += *(const f32x4*)(p + 4);
          }
          {
            const float* p = hb + (size_t)ea3 * 256 + kk;
            s0 += *(const f32x4*)p;
            s1 += *(const f32x4*)(p + 4);
          }
          u16x8 hv, lv;
#pragma unroll
          for (int z = 0; z < 4; ++z) {
            unsigned short h_, l_;
            split2(s0[z], h_, l_); hv[z] = h_; lv[z] = l_;
            split2(s1[z], h_, l_); hv[4 + z] = h_; lv[4 + z] = l_;
          }
          *(u16x8*)&AsH[srow * AP + sks + half * 8] = hv;
          *(u16x8*)&AsL[srow * AP + sks + half * 8] = lv;
        }
      } else {
        u16x8 hv0 = {0,0,0,0,0,0,0,0}, lv0 = {0,0,0,0,0,0,0,0};
        u16x8 hv1 = {0,0,0,0,0,0,0,0}, lv1 = {0,0,0,0,0,0,0,0};
#pragma unroll
        for (int z = 0; z < 16; ++z) {
          int k = k0 + z;
          float v = 0.f;
          if (AMODE == 0) {
            if (k < K) v = ((const float*)Aa_)[(size_t)row * lda + k];
          } else if (AMODE == 2) {
            if (k < 256) v = ((const float*)Aa_)[(size_t)row * 256 + k];
            else if (k < 354) v = ((const float*)Ab_)[(size_t)row * 98 + (k - 256)];
          } else if (AMODE == 8) {  // k0 >= 256 guaranteed here
            if (k < 354) v = ((const float*)Ab_)[(size_t)row * 98 + (k - 256)];
          } else {  // AMODE 7, k0 >= 512: prev_hid fp32
            v = Af32[(size_t)row * 256 + (k - 512)];
          }
          unsigned short h_, l_;
          split2(v, h_, l_);
          if (z < 8) { hv0[z] = h_; lv0[z] = l_; }
          else       { hv1[z - 8] = h_; lv1[z - 8] = l_; }
        }
        *(u16x8*)&AsH[srow * AP + sks]     = hv0;
        *(u16x8*)&AsH[srow * AP + sks + 8] = hv1;
        *(u16x8*)&AsL[srow * AP + sks]     = lv0;
        *(u16x8*)&AsL[srow * AP + sks + 8] = lv1;
      }
    }
    // ---- stage B ----
    {
      const int n = tileN + srow;
      if (n < N) {
        size_t bb = (size_t)n * ldb + k0;
        *(u16x8*)&BsH[srow * AP + sks]     = *(const u16x8*)&BTh[bb];
        *(u16x8*)&BsH[srow * AP + sks + 8] = *(const u16x8*)&BTh[bb + 8];
        *(u16x8*)&BsL[srow * AP + sks]     = *(const u16x8*)&BTl[bb];
        *(u16x8*)&BsL[srow * AP + sks + 8] = *(const u16x8*)&BTl[bb + 8];
      } else {
        u16x8 z8 = {0,0,0,0,0,0,0,0};
        *(u16x8*)&BsH[srow * AP + sks]     = z8;
        *(u16x8*)&BsH[srow * AP + sks + 8] = z8;
        *(u16x8*)&BsL[srow * AP + sks]     = z8;
        *(u16x8*)&BsL[srow * AP + sks + 8] = z8;
      }
    }
    __syncthreads();
    // ---- compute ----
    bf16x8 ah[4], al[4];
#pragma unroll
    for (int am = 0; am < 4; ++am) {
      int ar = wr + am * 16 + l15;
      ah[am] = *(const bf16x8*)&AsH[ar * AP + l4 * 8];
      if (AMODE != 6) al[am] = *(const bf16x8*)&AsL[ar * AP + l4 * 8];
    }
#pragma unroll
    for (int bn = 0; bn < 4; ++bn) {
      if (bn < bnMax) {
        int br = wc + bn * 16 + l15;
        bf16x8 bh = *(const bf16x8*)&BsH[br * AP + l4 * 8];
        bf16x8 bl = *(const bf16x8*)&BsL[br * AP + l4 * 8];
#pragma unroll
        for (int am = 0; am < 4; ++am) {
          acc[am][bn] = MFMA(ah[am], bh, acc[am][bn]);
          acc[am][bn] = MFMA(ah[am], bl, acc[am][bn]);
          if (AMODE != 6) acc[am][bn] = MFMA(al[am], bh, acc[am][bn]);
        }
      }
    }
  }

  // ---- epilogue ----
#pragma unroll
  for (int am = 0; am < 4; ++am) {
#pragma unroll
    for (int bn = 0; bn < 4; ++bn) {
      if (bn >= bnMax) continue;
      int col = tileN + wc + bn * 16 + l15;
      float bs = bias ? bias[col] : 0.f;
#pragma unroll
      for (int r = 0; r < 4; ++r) {
        size_t row = (size_t)tileM + wr + am * 16 + l4 * 4 + r;
        float v = acc[am][bn][r] + bs;
        if (addH) v += b2f(addH[row * 256 + col]) + b2f(addL[row * 256 + col]);
        if (relu) v = fmaxf(v, 0.f);
        if (outmode == 0) {
          unsigned short h_, l_;
          split2(v, h_, l_);
          ((unsigned short*)outA)[row * (size_t)ldco + col] = h_;
          ((unsigned short*)outB)[row * (size_t)ldco + col] = l_;
        } else if (outmode == 1) {
          ((float*)outA)[row * (size_t)ldco + outcol + col] = v;
        } else if (outmode == 2) {
          int mol = (int)(row >> 6), t = (int)(row & 63);
          ((float*)outA)[(size_t)mol * OUT_STRIDE + 4096 + t * 128 + col] = v;
        } else {
          int mol = (int)(row >> 7), u = (int)(row & 127);
          ((float*)outA)[(size_t)mol * OUT_STRIDE + u * 32 + col] = v;
        }
      }
    }
  }
}

// ---------------------------------------------------------------------------
// msg_f6: fused DMPNN iteration with DOUBLE-BUFFERED LDS + one barrier per
// chunk. Registers (64 VGPR + 64 AGPR acc) cap residency at 1 block/CU, so
// LDS has 86 KB of free headroom -> 2 x 73,728 B buffers cost nothing.
// Schedule per chunk c: barrier -> STAGE(c+1 -> buf[(c+1)&1]) -> MFMA(buf[c&1]).
// The barrier at top of iter c separates COMPUTE(c-1)'s reads of buf[(c+1)&1]
// from STAGE(c+1)'s writes (race-free); staging tail overlaps other waves'
// MFMA. 12 chunks: c<4 phase-1 (fbT@Wi, 2 MFMA/frag), c>=4 phase-2
// (m@Wh, 3 MFMA/frag); mid-relu after chunk 3. Math identical to msg_f4.
// ---------------------------------------------------------------------------
__launch_bounds__(1024)
__global__ void msg_f6(float* h,
                       const unsigned short* __restrict__ WhTh,
                       const unsigned short* __restrict__ WhTl,
                       const unsigned short* __restrict__ WiTh,
                       const unsigned short* __restrict__ WiTl,
                       const unsigned short* __restrict__ fbT) {
  extern __shared__ char smem_[];
  const int tid = threadIdx.x;
  const int lane = tid & 63, l15 = lane & 15, l4 = lane >> 4;
  const int w = tid >> 6;          // 0..15
  const int wm = (w >> 2) * 64;    // row base: 0,64,128,192
  const int wn = (w & 3) * 64;     // col base: 0,64,128,192
  const int mol = blockIdx.x;
  const int arow = tid >> 2;       // staging row 0..255 (edge id, identity)
  const int aks = (tid & 3) * 8;   // staging k sub-seg {0,8,16,24}

  f32x4 acc[4][4];
#pragma unroll
  for (int i = 0; i < 4; ++i)
#pragma unroll
    for (int j = 0; j < 4; ++j) acc[i][j] = (f32x4){0.f, 0.f, 0.f, 0.f};

  const int sA = e_src(arow);
  const int rvA = (arow < 128) ? (arow + 128) : (arow - 128);
  const int i0 = (sA + 63) & 63;
  const int i1 = 64 + ((sA + 62) & 63);
  const int i2 = 128 + sA;
  const int i3 = 192 + sA;
  const size_t hbase = (size_t)mol * 256 * 256;
  const size_t fbb = (size_t)(mol * 256 + arow) * 128;

  // ---- STAGE chunk c into buffer b ----
  auto STAGE = [&](int b, int c) {
    unsigned short* AsC = (unsigned short*)(smem_ + b * BUFB);
    unsigned short* BsC = (unsigned short*)(smem_ + b * BUFB + 36864);
    if (c < 4) {
      // phase 1: A = fbT (single plane), B = Wi (pitch 128)
      *(u16x8*)&AsC[arow * CP + aks] = *(const u16x8*)&fbT[fbb + c * 32 + aks];
      size_t bb = (size_t)arow * 128 + c * 32 + aks;
      *(u16x8*)&BsC[arow * CP + aks]      = *(const u16x8*)&WiTh[bb];
      *(u16x8*)&BsC[arow * CP + 32 + aks] = *(const u16x8*)&WiTl[bb];
    } else {
      // phase 2: A = m (fused a_sum, split), B = Wh (pitch 256)
      const int c0 = (c - 4) * 32 + aks;
      f32x4 m0, m1;
      {
        const float* p = &h[hbase + (size_t)i0 * 256 + c0];
        m0 = *(const f32x4*)p;
        m1 = *(const f32x4*)(p + 4);
      }
      {
        const float* p = &h[hbase + (size_t)i1 * 256 + c0];
        m0 += *(const f32x4*)p;
        m1 += *(const f32x4*)(p + 4);
      }
      {
        const float* p = &h[hbase + (size_t)i2 * 256 + c0];
        m0 += *(const f32x4*)p;
        m1 += *(const f32x4*)(p + 4);
      }
      {
        const float* p = &h[hbase + (size_t)i3 * 256 + c0];
        m0 += *(const f32x4*)p;
        m1 += *(const f32x4*)(p + 4);
      }
      {
        const float* p = &h[hbase + (size_t)rvA * 256 + c0];
        m0 -= *(const f32x4*)p;
        m1 -= *(const f32x4*)(p + 4);
      }
      u16x8 hv, lv;
#pragma unroll
      for (int z = 0; z < 4; ++z) {
        unsigned short h_, l_;
        split2(m0[z], h_, l_); hv[z] = h_; lv[z] = l_;
        split2(m1[z], h_, l_); hv[4 + z] = h_; lv[4 + z] = l_;
      }
      *(u16x8*)&AsC[arow * CP + aks]      = hv;
      *(u16x8*)&AsC[arow * CP + 32 + aks] = lv;
      size_t bb = (size_t)arow * 256 + (c - 4) * 32 + aks;
      *(u16x8*)&BsC[arow * CP + aks]      = *(const u16x8*)&WhTh[bb];
      *(u16x8*)&BsC[arow * CP + 32 + aks] = *(const u16x8*)&WhTl[bb];
    }
  };

  // ---- COMPUTE chunk c from buffer b ----
  auto COMPUTE = [&](int b, int c) {
    unsigned short* AsC = (unsigned short*)(smem_ + b * BUFB);
    unsigned short* BsC = (unsigned short*)(smem_ + b * BUFB + 36864);
    if (c < 4) {
      bf16x8 ah[4];
#pragma unroll
      for (int am = 0; am < 4; ++am) {
        int ar = wm + am * 16 + l15;
        ah[am] = *(const bf16x8*)&AsC[ar * CP + l4 * 8];
      }
#pragma unroll
      for (int bn = 0; bn < 4; ++bn) {
        int br = wn + bn * 16 + l15;
        bf16x8 bh = *(const bf16x8*)&BsC[br * CP + l4 * 8];
        bf16x8 bl = *(const bf16x8*)&BsC[br * CP + 32 + l4 * 8];
#pragma unroll
        for (int am = 0; am < 4; ++am) {
          acc[am][bn] = MFMA(ah[am], bh, acc[am][bn]);
          acc[am][bn] = MFMA(ah[am], bl, acc[am][bn]);
        }
      }
    } else {
      bf16x8 ah[4], al[4];
#pragma unroll
      for (int am = 0; am < 4; ++am) {
        int ar = wm + am * 16 + l15;
        ah[am] = *(const bf16x8*)&AsC[ar * CP + l4 * 8];
        al[am] = *(const bf16x8*)&AsC[ar * CP + 32 + l4 * 8];
      }
#pragma unroll
      for (int bn = 0; bn < 4; ++bn) {
        int br = wn + bn * 16 + l15;
        bf16x8 bh = *(const bf16x8*)&BsC[br * CP + l4 * 8];
        bf16x8 bl = *(const bf16x8*)&BsC[br * CP + 32 + l4 * 8];
#pragma unroll
        for (int am = 0; am < 4; ++am) {
          acc[am][bn] = MFMA(ah[am], bh, acc[am][bn]);
          acc[am][bn] = MFMA(ah[am], bl, acc[am][bn]);
          acc[am][bn] = MFMA(al[am], bh, acc[am][bn]);
        }
      }
    }
  };

  STAGE(0, 0);
  for (int c = 0; c < 12; ++c) {
    __syncthreads();
    if (c + 1 < 12) STAGE((c + 1) & 1, c + 1);
    COMPUTE(c & 1, c);
    if (c == 3) {
      // mid-relu: acc holds h0
#pragma unroll
      for (int i = 0; i < 4; ++i)
#pragma unroll
        for (int j = 0; j < 4; ++j)
#pragma unroll
          for (int r = 0; r < 4; ++r) acc[i][j][r] = fmaxf(acc[i][j][r], 0.f);
    }
  }

  // ---- epilogue: h = relu(acc) fp32, in-place (block owns its rows; all
  // global h reads happened in STAGE calls before the last barrier) ----
#pragma unroll
  for (int am = 0; am < 4; ++am) {
#pragma unroll
    for (int r = 0; r < 4; ++r) {
      int row = wm + am * 16 + l4 * 4 + r;
      size_t rowb = hbase + (size_t)row * 256;
#pragma unroll
      for (int bn = 0; bn < 4; ++bn) {
        int col = wn + bn * 16 + l15;
        h[rowb + col] = fmaxf(acc[am][bn][r], 0.f);
      }
    }
  }
}

// flash attention, fp32 qkv in, split ctx out: one wave per (mol, head)
__global__ __launch_bounds__(64) void attn_k(const float* __restrict__ qkv,
                                             unsigned short* __restrict__ ctxH,
                                             unsigned short* __restrict__ ctxL) {
  __shared__ float kls[64 * 32];
  __shared__ float vls[64 * 32];
  int mol = blockIdx.x >> 3, head = blockIdx.x & 7;
  int lane = threadIdx.x;
  size_t rb = ((size_t)(mol * 64 + lane)) * 768 + head * 32;
#pragma unroll
  for (int c = 0; c < 8; ++c) {
    *(float4*)(kls + lane * 32 + c * 4) = *(const float4*)(qkv + rb + 256 + c * 4);
    *(float4*)(vls + lane * 32 + c * 4) = *(const float4*)(qkv + rb + 512 + c * 4);
  }
  float q[32];
#pragma unroll
  for (int d = 0; d < 32; ++d) q[d] = qkv[rb + d];
  __syncthreads();
  float mx = -1e30f, l = 0.f;
  float acc[32];
#pragma unroll
  for (int d = 0; d < 32; ++d) acc[d] = 0.f;
  for (int j = 0; j < 64; ++j) {
    float s = 0.f;
#pragma unroll
    for (int d = 0; d < 32; ++d) s += q[d] * kls[j * 32 + d];
    s *= 0.17677669529663687f;  // 1/sqrt(32)
    float nm = fmaxf(mx, s);
    float co = __expf(mx - nm);
    float p = __expf(s - nm);
    l = l * co + p;
#pragma unroll
    for (int d = 0; d < 32; ++d) acc[d] = acc[d] * co + p * vls[j * 32 + d];
    mx = nm;
  }
  float inv = 1.f / l;
  size_t ob = ((size_t)(mol * 64 + lane)) * 256 + head * 32;
#pragma unroll
  for (int d = 0; d < 32; ++d) {
    unsigned short h_, l_;
    split2(acc[d] * inv, h_, l_);
    ctxH[ob + d] = h_;
    ctxL[ob + d] = l_;
  }
}

// merged graph head: gv in-block, then relu(gv@G1+g1)@G2+g2
__global__ __launch_bounds__(512) void gvh_k(const unsigned short* __restrict__ afH,
                                             const unsigned short* __restrict__ afL,
                                             const float* __restrict__ G1,
                                             const float* __restrict__ g1,
                                             const float* __restrict__ G2,
                                             const float* __restrict__ g2,
                                             float* __restrict__ out) {
  __shared__ float xs[256];
  __shared__ float red[512];
  int mol = blockIdx.x, j = threadIdx.x;
  if (j < 256) {
    float s = 0.f;
    for (int a = 0; a < 64; ++a) {
      size_t i = ((size_t)mol * 64 + a) * 256 + j;
      s += b2f(afH[i]) + b2f(afL[i]);
    }
    xs[j] = s;
  }
  __syncthreads();
  float s = 0.f;
  for (int k = 0; k < 256; ++k) s += xs[k] * G1[k * 512 + j];
  s = fmaxf(s + g1[j], 0.f);
  red[j] = s * G2[j];
  __syncthreads();
  for (int st = 256; st > 0; st >>= 1) {
    if (j < st) red[j] += red[j + st];
    __syncthreads();
  }
  if (j == 0) out[(size_t)mol * OUT_STRIDE + 12288] = red[0] + g2[0];
}

extern "C" void kernel_launch(void* const* d_in, const int* in_sizes, int n_in,
                              void* d_out, int out_size, void* d_ws, size_t ws_size,
                              hipStream_t stream) {
  (void)in_sizes; (void)n_in; (void)out_size; (void)ws_size;
  const float* f_atoms  = (const float*)d_in[0];
  const float* f_bonds  = (const float*)d_in[1];
  const float* prev_hid = (const float*)d_in[2];
  const float* W_i   = (const float*)d_in[7];
  const float* W_h   = (const float*)d_in[8];
  const float* W_o   = (const float*)d_in[9];
  const float* b_o   = (const float*)d_in[10];
  const float* Wq    = (const float*)d_in[11];
  const float* Wk    = (const float*)d_in[12];
  const float* Wv    = (const float*)d_in[13];
  const float* Wattn = (const float*)d_in[14];
  const float* W_vv  = (const float*)d_in[15];
  const float* W_vc  = (const float*)d_in[16];
  const float* A1    = (const float*)d_in[17];
  const float* a1    = (const float*)d_in[18];
  const float* A2    = (const float*)d_in[19];
  const float* a2    = (const float*)d_in[20];
  const float* B1    = (const float*)d_in[21];
  const float* b1    = (const float*)d_in[22];
  const float* B2    = (const float*)d_in[23];
  const float* b2b   = (const float*)d_in[24];
  const float* G1    = (const float*)d_in[25];
  const float* g1    = (const float*)d_in[26];
  const float* G2    = (const float*)d_in[27];
  const float* g2    = (const float*)d_in[28];
  float* out = (float*)d_out;

  // ---- workspace (~172.8 MB < known-good 187.3) ----
  char* base = (char*)d_ws;
  float* h = (float*)(base);                                   // 134.2 MB fp32
  unsigned short* fbT = (unsigned short*)(base + 134217728);   // steps 0-2 (32 MB)
  char* W0 = base + 167772160;                                 // weights ~5.1 MB
  unsigned short* WiTh   = (unsigned short*)(W0);
  unsigned short* WiTl   = (unsigned short*)(W0 + 65536);
  unsigned short* WhTh   = (unsigned short*)(W0 + 131072);
  unsigned short* WhTl   = (unsigned short*)(W0 + 262144);
  unsigned short* WoTh   = (unsigned short*)(W0 + 393216);
  unsigned short* WoTl   = (unsigned short*)(W0 + 589824);
  unsigned short* WqkvTh = (unsigned short*)(W0 + 786432);     // [768][256]
  unsigned short* WqkvTl = (unsigned short*)(W0 + 1179648);
  unsigned short* WaTh   = (unsigned short*)(W0 + 1572864);    // (unused, kept)
  unsigned short* WaTl   = (unsigned short*)(W0 + 1703936);
  unsigned short* Wcv2Th = (unsigned short*)(W0 + 1835008);    // [256][768]
  unsigned short* Wcv2Tl = (unsigned short*)(W0 + 2228224);
  unsigned short* A1Th   = (unsigned short*)(W0 + 2621440);
  unsigned short* A1Tl   = (unsigned short*)(W0 + 2883584);
  unsigned short* A2Th   = (unsigned short*)(W0 + 3145728);
  unsigned short* A2Tl   = (unsigned short*)(W0 + 3276800);
  unsigned short* B1bTh  = (unsigned short*)(W0 + 3407872);    // [1024][256]
  unsigned short* B1bTl  = (unsigned short*)(W0 + 3932160);
  unsigned short* B2Th   = (unsigned short*)(W0 + 4456448);
  unsigned short* B2Tl   = (unsigned short*)(W0 + 4489216);
  // post-loop aliases (lifetimes audited):
  unsigned short* xAh  = (unsigned short*)(base + 134217728);
  unsigned short* xAl  = (unsigned short*)(base + 150994944);
  float* qkv           = (float*)(base + 33554432);
  unsigned short* ctxh = (unsigned short*)(base);
  unsigned short* ctxl = (unsigned short*)(base + 16777216);
  unsigned short* atfh = (unsigned short*)(base + 67108864);
  unsigned short* atfl = (unsigned short*)(base + 83886080);
  unsigned short* t1h  = (unsigned short*)(base);
  unsigned short* t1l  = (unsigned short*)(base + 33554432);
  unsigned short* Ph   = (unsigned short*)(base);
  unsigned short* Pl   = (unsigned short*)(base + 100663296);

  // 0) all weight pre-converts + composed Wcv2 + B1b remap + f_bonds plane
  convAll<<<7840, 256, 0, stream>>>(
      W_i, W_h, W_o, Wq, Wk, Wv, Wattn, W_vc, W_vv, A1, A2, B1, B2,
      f_bonds, fbT,
      WiTh, WiTl, WhTh, WhTl, WoTh, WoTl, WqkvTh, WqkvTl, WaTh, WaTl,
      Wcv2Th, Wcv2Tl, A1Th, A1Tl, A2Th, A2Tl, B1bTh, B1bTl, B2Th, B2Tl);

  // 1) h = h0 = relu(fbT @ W_i)  (single-plane A, fp32 out)
  mgemm<6><<<dim3(1024, 2), 256, 0, stream>>>(
      fbT, nullptr, nullptr, nullptr, nullptr, WiTh, WiTl, 128,
      nullptr, nullptr, nullptr, nullptr,
      h, nullptr, N_DIR, 256, 128, 128, 256, 0, 1, 1);

  // 2) DMPNN loop: multi-launch msg_f6 (double-buffered LDS, 1 barrier/chunk)
  for (int d = 0; d < 9; ++d) {
    msg_f6<<<512, 1024, 2 * BUFB, stream>>>(h, WhTh, WhTl, WiTh, WiTl, fbT);
  }

  // 3+4) a_feats = relu([a_sum(h) | f_atoms] @ WoT + b_o)  (a_sum fused)
  mgemm<8><<<dim3(256, 2), 256, 0, stream>>>(
      nullptr, f_atoms, nullptr, nullptr, h, WoTh, WoTl, 384,
      nullptr, nullptr, b_o, nullptr,
      xAh, xAl, N_ATOMS, 256, 354, 0, 256, 0, 1, 0);
  // 5) qkv fused (N=768, fp32 out)
  mgemm<1><<<dim3(256, 6), 256, 0, stream>>>(
      xAh, xAl, nullptr, nullptr, nullptr, WqkvTh, WqkvTl, 256,
      nullptr, nullptr, nullptr, nullptr,
      qkv, nullptr, N_ATOMS, 768, 256, 256, 768, 0, 0, 1);
  // 6) attention
  attn_k<<<4096, 64, 0, stream>>>(qkv, ctxh, ctxl);
  // 7+8) atom_feats = relu(ctx@Wac + xA@Wvc^T + prev@Wvv^T)  (K=768 fused)
  mgemm<7><<<dim3(256, 2), 256, 0, stream>>>(
      ctxh, ctxl, xAh, xAl, prev_hid, Wcv2Th, Wcv2Tl, 768,
      nullptr, nullptr, nullptr, nullptr,
      atfh, atfl, N_ATOMS, 256, 768, 256, 256, 0, 1, 0);
  // 9) atom head
  mgemm<1><<<dim3(256, 4), 256, 0, stream>>>(
      atfh, atfl, nullptr, nullptr, nullptr, A1Th, A1Tl, 256,
      nullptr, nullptr, a1, nullptr,
      t1h, t1l, N_ATOMS, 512, 256, 256, 512, 0, 1, 0);
  mgemm<1><<<dim3(256, 1), 256, 0, stream>>>(
      t1h, t1l, nullptr, nullptr, nullptr, A2Th, A2Tl, 512,
      nullptr, nullptr, a2, nullptr,
      out, nullptr, N_ATOMS, 128, 512, 512, 0, 0, 0, 2);
  // 10) bond head: unified P = atomf @ B1b (N=1024: [P1 | P2])
  mgemm<1><<<dim3(256, 8), 256, 0, stream>>>(
      atfh, atfl, nullptr, nullptr, nullptr, B1bTh, B1bTl, 256,
      nullptr, nullptr, nullptr, nullptr,
      Ph, Pl, N_ATOMS, 1024, 256, 256, 1024, 0, 0, 0);
  //     out_bond = relu(P[a0][k] + P[a1][512+k] + b1) @ B2 + b2b
  mgemm<5><<<dim3(512, 1), 256, 0, stream>>>(
      Ph, Pl, nullptr, nullptr, nullptr, B2Th, B2Tl, 512,
      nullptr, nullptr, b2b, b1,
      out, nullptr, N_UND, 32, 512, 0, 0, 0, 0, 3);
  // 11) graph head (gv + MLP merged)
  gvh_k<<<512, 512, 0, stream>>>(atfh, atfl, G1, g1, G2, g2, out);
}